// Round 18
// baseline (10866.960 us; speedup 1.0000x reference)
//
#include <hip/hip_runtime.h>
#include <math.h>

#define B_SZ 128
#define T_SZ 128
#define EMBD 300
#define ND 512
#define G3 1536
#define FPAD 32    // flag padding stride (u32s) = 128 B
#define NFID 128   // flag ids per replica
#define NREP 8     // flag replicas
#define SPAD 132   // padded q-segment stride (floats): bank shift 4 per q

typedef short s16x8 __attribute__((ext_vector_type(8)));
typedef float f32x4 __attribute__((ext_vector_type(4)));
typedef unsigned u32x4 __attribute__((ext_vector_type(4)));
typedef unsigned long long u64;

__device__ __forceinline__ unsigned short f2b(float x) {
    unsigned u = __float_as_uint(x);
    unsigned r = (u + 0x7fff + ((u >> 16) & 1)) >> 16;  // RNE
    return (unsigned short)r;
}
__device__ __forceinline__ float b2f(unsigned short v) {
    return __uint_as_float(((unsigned)v) << 16);
}
__device__ __forceinline__ unsigned pk2(float lo, float hi) {
    return (unsigned)f2b(lo) | ((unsigned)f2b(hi) << 16);
}
__device__ __forceinline__ float fsigmoid(float x) { return 1.0f / (1.0f + __expf(-x)); }
__device__ __forceinline__ float ftanh(float x) { return 1.0f - 2.0f / (__expf(2.0f * x) + 1.0f); }

// packed bf16 dot2: c += a.lo*b.lo + a.hi*b.hi (single VOP3P instruction)
__device__ __forceinline__ float dot2bf(unsigned a, unsigned b, float c) {
    asm("v_dot2_f32_bf16 %0, %1, %2, %0" : "+v"(c) : "v"(a), "v"(b));
    return c;
}

__device__ __forceinline__ f32x4 mfma16(s16x8 a, s16x8 b, f32x4 c) {
    return __builtin_amdgcn_mfma_f32_16x16x32_bf16(a, b, c, 0, 0, 0);
}

// ---- coherent (LLC-point, fence-free) helpers (GRU chains only) ----
__device__ __forceinline__ u64 cld64(const void* p) {
    return __hip_atomic_load((const u64*)p, __ATOMIC_RELAXED, __HIP_MEMORY_SCOPE_AGENT);
}
__device__ __forceinline__ void cst64(void* p, u64 v) {
    __hip_atomic_store((u64*)p, v, __ATOMIC_RELAXED, __HIP_MEMORY_SCOPE_AGENT);
}
__device__ __forceinline__ unsigned cld32(const void* p) {
    return __hip_atomic_load((const unsigned*)p, __ATOMIC_RELAXED, __HIP_MEMORY_SCOPE_AGENT);
}
__device__ __forceinline__ void cst32(void* p, unsigned v) {
    __hip_atomic_store((unsigned*)p, v, __ATOMIC_RELAXED, __HIP_MEMORY_SCOPE_AGENT);
}
__device__ __forceinline__ s16x8 cld_frag(const unsigned short* p) {
    union { u64 q[2]; s16x8 v; } u;
    u.q[0] = cld64(p);
    u.q[1] = cld64(p + 4);
    return u.v;
}

// ---- replicated-flag grid barrier (GRU chains) ----
__device__ __forceinline__ void postflag(unsigned* flags, int base, int id, unsigned ep)
{
    if (threadIdx.x < NREP)
        cst32(&flags[((long)threadIdx.x * NFID + base + id) * FPAD], ep);
}
__device__ __forceinline__ void waitflags(const unsigned* flags, int base, int n,
                                          unsigned ep, int rep)
{
    const unsigned* fr = flags + (long)rep * NFID * FPAD;
    if (threadIdx.x < 64) {
#pragma unroll 1
        for (int i = threadIdx.x; i < n; i += 64)
            while (cld32(&fr[(long)(base + i) * FPAD]) < ep)
                __builtin_amdgcn_s_sleep(2);
    }
    __syncthreads();
}
__device__ __forceinline__ void fbar(unsigned* flags, int base, int nb, unsigned ep)
{
    __syncthreads();
    postflag(flags, base, blockIdx.x & 63, ep);
    waitflags(flags, base, nb, ep, blockIdx.x & 7);
}

#define FB_GRUP 0
#define FB_GRUH 64

// ---------------- generic MFMA GEMM (precompute only) ----------------
template<typename AT, bool OB>
__global__ __launch_bounds__(256)
void mfma_gemm(const AT* __restrict__ A, const int* __restrict__ idxA,
               const unsigned short* __restrict__ Wb, const float* __restrict__ bias,
               void* __restrict__ Cv,
               int M, int N, int K, int ldA, int Kpad, int ldC)
{
    __shared__ unsigned short As[64][40];
    __shared__ unsigned short Bs[64][40];
    const int tid = threadIdx.x;
    const int wv = tid >> 6, lane = tid & 63;
    const int wm = wv >> 1, wn = wv & 1;
    const int m0 = blockIdx.y * 64, n0 = blockIdx.x * 64;

    f32x4 acc[2][2] = {{{0.f,0.f,0.f,0.f},{0.f,0.f,0.f,0.f}},
                       {{0.f,0.f,0.f,0.f},{0.f,0.f,0.f,0.f}}};
    const int r_st = tid >> 2, k_st = (tid & 3) * 8;

    long arow = -1;
    {
        int gm = m0 + r_st;
        if (gm < M) arow = idxA ? (long)idxA[gm] : (long)gm;
    }

    const int kIters = (K + 31) / 32;
    for (int it = 0; it < kIters; ++it) {
        const int kg = it * 32 + k_st;
        {
            s16x8 pk = {0,0,0,0,0,0,0,0};
            if (arow >= 0) {
                if constexpr (sizeof(AT) == 2) {
                    if (kg + 8 <= K) {
                        pk = *(const s16x8*)((const unsigned short*)A + arow * (long)ldA + kg);
                    } else {
#pragma unroll
                        for (int j = 0; j < 8; ++j)
                            if (kg + j < K) pk[j] = (short)((const unsigned short*)A)[arow * (long)ldA + kg + j];
                    }
                } else {
                    if (kg + 8 <= K) {
                        const float* p = (const float*)A + arow * (long)ldA + kg;
                        f32x4 u0 = *(const f32x4*)p;
                        f32x4 u1 = *(const f32x4*)(p + 4);
#pragma unroll
                        for (int j = 0; j < 4; ++j) { pk[j] = (short)f2b(u0[j]); pk[4+j] = (short)f2b(u1[j]); }
                    } else {
#pragma unroll
                        for (int j = 0; j < 8; ++j) {
                            int kk = kg + j;
                            if (kk < K) pk[j] = (short)f2b(((const float*)A)[arow * (long)ldA + kk]);
                        }
                    }
                }
            }
            *(s16x8*)&As[r_st][k_st] = pk;
        }
        {
            int gn = n0 + r_st;
            s16x8 pk = {0,0,0,0,0,0,0,0};
            if (gn < N) pk = *(const s16x8*)&Wb[(long)gn * Kpad + kg];
            *(s16x8*)&Bs[r_st][k_st] = pk;
        }
        __syncthreads();
        {
            const int koff = (lane >> 4) * 8;
            s16x8 af[2], bfr[2];
#pragma unroll
            for (int f = 0; f < 2; ++f) {
                af[f]  = *(s16x8*)&As[wm * 32 + f * 16 + (lane & 15)][koff];
                bfr[f] = *(s16x8*)&Bs[wn * 32 + f * 16 + (lane & 15)][koff];
            }
#pragma unroll
            for (int fi = 0; fi < 2; ++fi)
#pragma unroll
                for (int fj = 0; fj < 2; ++fj)
                    acc[fi][fj] = mfma16(af[fi], bfr[fj], acc[fi][fj]);
        }
        __syncthreads();
    }
#pragma unroll
    for (int fi = 0; fi < 2; ++fi)
#pragma unroll
        for (int fj = 0; fj < 2; ++fj)
#pragma unroll
            for (int r = 0; r < 4; ++r) {
                int m = m0 + wm * 32 + fi * 16 + (lane >> 4) * 4 + r;
                int n = n0 + wn * 32 + fj * 16 + (lane & 15);
                if (m < M && n < N) {
                    float v = acc[fi][fj][r];
                    if (bias) v += bias[n];
                    if constexpr (OB) ((unsigned short*)Cv)[(long)m * ldC + n] = f2b(v);
                    else               ((float*)Cv)[(long)m * ldC + n] = v;
                }
            }
}

// ---------------- persistent GRU chain (unchanged) ----------------
#define GRU_NB 64
__global__ __launch_bounds__(256, 1)
void gru_chain(const unsigned short* __restrict__ Whh_b, const float* __restrict__ GI,
               const float* __restrict__ bhh, const int* __restrict__ toks,
               float* __restrict__ h32,
               unsigned short* __restrict__ h16a, unsigned short* __restrict__ h16b,
               unsigned short* __restrict__ o_bt,
               unsigned* __restrict__ flags, int fbase)
{
    __shared__ unsigned short wlds[3][16][512];   // 48 KB
    __shared__ unsigned short ht[64][20];
    const int tid = threadIdx.x;
    const int wv = tid >> 6, lane = tid & 63;
    const int dt = blockIdx.x & 31, bh = blockIdx.x >> 5;
    const int b0 = bh * 64;

    for (int s = 0; s < 12; ++s) {
        int slot = tid + s * 256;
        int g = slot >> 10, rem = slot & 1023, ks = rem >> 6, ln = rem & 63;
        int row = g * ND + dt * 16 + (ln & 15);
        int k = ks * 32 + (ln >> 4) * 8;
        *(s16x8*)&wlds[g][ks][ln * 8] = *(const s16x8*)&Whh_b[(long)row * ND + k];
    }
    __syncthreads();

    const int d = dt * 16 + (lane & 15);
    const int brow = b0 + wv * 16 + (lane >> 4) * 4;
    const long fhrd = ((long)(bh * 4 + wv) * 16) << 9;

    const int bl = tid & 63, dq = tid >> 6;
    const long fhwr = (((long)(bh * 4 + (bl >> 4)) * 16 + (dt >> 1)) << 9)
                    + (((((dt & 1) * 16 + dq * 4) >> 3) * 16 + (bl & 15)) * 8)
                    + (((dt & 1) * 16 + dq * 4) & 7);

    float hreg[4];
#pragma unroll
    for (int rr = 0; rr < 4; ++rr) hreg[rr] = h32[(long)(brow + rr) * ND + d];

    float o_run[4] = {0.f, 0.f, 0.f, 0.f};
    unsigned ep = 0;

    for (int t = 0; t < T_SZ; ++t) {
        const unsigned short* hin16 = (t & 1) ? h16b : h16a;
        unsigned short* hout16 = (t & 1) ? h16a : h16b;

        const float* git = GI + (long)t * (B_SZ * G3);
        float gi_r[4], gi_z[4], gi_n[4]; int mk[4];
#pragma unroll
        for (int rr = 0; rr < 4; ++rr) {
            int b = brow + rr;
            gi_r[rr] = git[(long)b * G3 + d];
            gi_z[rr] = git[(long)b * G3 + ND + d];
            gi_n[rr] = git[(long)b * G3 + 2 * ND + d];
            mk[rr]   = toks[b * T_SZ + t];
        }

        f32x4 acc0 = {0,0,0,0}, acc1 = {0,0,0,0}, acc2 = {0,0,0,0};
#pragma unroll
        for (int ks = 0; ks < 16; ++ks) {
            s16x8 a  = cld_frag(&hin16[fhrd + ((long)ks << 9) + lane * 8]);
            s16x8 br = *(s16x8*)&wlds[0][ks][lane * 8];
            s16x8 bz = *(s16x8*)&wlds[1][ks][lane * 8];
            s16x8 bn = *(s16x8*)&wlds[2][ks][lane * 8];
            acc0 = mfma16(a, br, acc0);
            acc1 = mfma16(a, bz, acc1);
            acc2 = mfma16(a, bn, acc2);
        }

#pragma unroll
        for (int rr = 0; rr < 4; ++rr) {
            int b = brow + rr;
            float rg = fsigmoid(gi_r[rr] + acc0[rr] + bhh[d]);
            float zg = fsigmoid(gi_z[rr] + acc1[rr] + bhh[ND + d]);
            float ng = ftanh(gi_n[rr] + rg * (acc2[rr] + bhh[2 * ND + d]));
            float hr = (1.0f - zg) * ng + zg * hreg[rr];
            bool m = mk[rr] != 0;
            float hn = m ? hr : hreg[rr];
            hreg[rr] = hn;
            ht[b - b0][lane & 15] = f2b(hn);
            if (t == T_SZ - 1) h32[(long)b * ND + d] = hn;
            o_run[rr] = (t == 0) ? hr : (m ? hr : o_run[rr]);
            o_bt[((long)b * T_SZ + t) * ND + d] = f2b(o_run[rr]);
        }
        __syncthreads();
        {
            u64 v = *(u64*)&ht[bl][dq * 4];
            cst64(&hout16[fhwr], v);
        }
        fbar(flags, fbase, GRU_NB, ++ep);
    }
}

// ---------------- sync-free per-batch match: padded LDS + deep prefetch ----------------
// Ws: [64][512][8]  bf16; Wg: [6][64][512][8] fam: 0 R_a, 1 Z_a, 2 N_a, 3 R_r, 4 Z_r, 5 N_r
__global__ __launch_bounds__(512, 1)
void match_pb(const unsigned short* __restrict__ Ws,
              const unsigned short* __restrict__ Wg,
              const unsigned short* __restrict__ OHWh_bt,
              const unsigned short* __restrict__ OHGI_bt,
              const float* __restrict__ m_bhh, const float* __restrict__ Walpha,
              const unsigned short* __restrict__ Yw_bb,
              const unsigned short* __restrict__ Y_bb,
              const int* __restrict__ prem, const int* __restrict__ hyp,
              float* __restrict__ r32)
{
    __shared__ unsigned ytp[64][512];   // 128 KB: Y tp-pair packed [tp/2][n]
    __shared__ float sarr[4 * SPAD];    // padded q-segments (bank-shifted)
    __shared__ float wal[4 * SPAD];
    __shared__ float part[512];
    __shared__ float lg[T_SZ];
    __shared__ unsigned lgp[64];
    __shared__ unsigned xa16[256];      // a packed bf16 pairs
    __shared__ unsigned xr16[256];      // r packed bf16 pairs
    __shared__ float xr32[512];         // r f32 (recurrence blend)

    const int b = blockIdx.x;
    const int tid = threadIdx.x;   // 0..511
    const int tp = tid >> 2, q = tid & 3;

    // Y -> tp-pair packed LDS (once)
    for (int s = 0; s < 8; ++s) {
        int idx = s * 512 + tid;            // 4096 jobs: rp 0..63, ng 0..63
        int rp = idx >> 6, n0 = (idx & 63) * 8;
        s16x8 y0 = *(const s16x8*)&Y_bb[((long)b * T_SZ + 2 * rp) * ND + n0];
        s16x8 y1 = *(const s16x8*)&Y_bb[((long)b * T_SZ + 2 * rp + 1) * ND + n0];
#pragma unroll
        for (int j = 0; j < 8; ++j)
            ytp[rp][n0 + j] = (unsigned)(unsigned short)y0[j]
                            | ((unsigned)(unsigned short)y1[j] << 16);
    }
    // Yw slice -> registers (once)
    s16x8 ywr[16];
#pragma unroll
    for (int i8 = 0; i8 < 16; ++i8)
        ywr[i8] = *(const s16x8*)&Yw_bb[((long)b * T_SZ + tp) * ND + q * 128 + i8 * 8];

    wal[(tid >> 7) * SPAD + (tid & 127)] = Walpha[tid];
    xr32[tid] = 0.0f;
    if (tid < 256) xr16[tid] = 0u;
    float mm = 0.f;
    if (tid < T_SZ) mm = (prem[b * T_SZ + tid] != 0) ? 0.f : 1000.f;
    __syncthreads();

    const float* sp  = &sarr[q * SPAD];
    const float* wap = &wal[q * SPAD];
    const int sw = (tid >> 7) * SPAD + (tid & 127);    // padded write slot for n = tid
    const u32x4* wsp4 = (const u32x4*)((const unsigned*)Ws + tid * 4);   // stride 512 per k8
    const u32x4* wgp4 = (const u32x4*)((const unsigned*)Wg + tid * 4);
    const u32x4* xa4 = (const u32x4*)xa16;
    const u32x4* xr4 = (const u32x4*)xr16;
    const unsigned ONE2 = 0x3F803F80u;

    for (int t = 0; t < T_SZ; ++t) {
        // ---- phase 1: s[n] = r . W_r[:,n] + OHWh (4-group double-buffered loads) ----
        {
            float acc = 0.f;
            u32x4 sA0, sA1, sA2, sA3, sB0, sB1, sB2, sB3;
            sA0 = wsp4[0 * 512]; sA1 = wsp4[1 * 512];
            sA2 = wsp4[2 * 512]; sA3 = wsp4[3 * 512];
#pragma unroll
            for (int g8 = 0; g8 < 8; ++g8) {
                const int kA = g8 * 8, kB = g8 * 8 + 4;
                // prefetch B-group (kB..kB+3)
                sB0 = wsp4[(long)(kB + 0) * 512]; sB1 = wsp4[(long)(kB + 1) * 512];
                sB2 = wsp4[(long)(kB + 2) * 512]; sB3 = wsp4[(long)(kB + 3) * 512];
                {
                    u32x4 x0 = xr4[kA], x1 = xr4[kA + 1], x2 = xr4[kA + 2], x3 = xr4[kA + 3];
#pragma unroll
                    for (int j = 0; j < 4; ++j) acc = dot2bf(sA0[j], x0[j], acc);
#pragma unroll
                    for (int j = 0; j < 4; ++j) acc = dot2bf(sA1[j], x1[j], acc);
#pragma unroll
                    for (int j = 0; j < 4; ++j) acc = dot2bf(sA2[j], x2[j], acc);
#pragma unroll
                    for (int j = 0; j < 4; ++j) acc = dot2bf(sA3[j], x3[j], acc);
                }
                // prefetch next A-group (kB+4..kB+7)
                if (g8 < 7) {
                    sA0 = wsp4[(long)(kB + 4) * 512]; sA1 = wsp4[(long)(kB + 5) * 512];
                    sA2 = wsp4[(long)(kB + 6) * 512]; sA3 = wsp4[(long)(kB + 7) * 512];
                }
                {
                    u32x4 x0 = xr4[kB], x1 = xr4[kB + 1], x2 = xr4[kB + 2], x3 = xr4[kB + 3];
#pragma unroll
                    for (int j = 0; j < 4; ++j) acc = dot2bf(sB0[j], x0[j], acc);
#pragma unroll
                    for (int j = 0; j < 4; ++j) acc = dot2bf(sB1[j], x1[j], acc);
#pragma unroll
                    for (int j = 0; j < 4; ++j) acc = dot2bf(sB2[j], x2[j], acc);
#pragma unroll
                    for (int j = 0; j < 4; ++j) acc = dot2bf(sB3[j], x3[j], acc);
                }
            }
            sarr[sw] = acc + b2f(OHWh_bt[((long)b * T_SZ + t) * ND + tid]);
        }
        __syncthreads();
        // ---- phase 2: logits (Yw regs, padded conflict-free LDS) ----
        {
            float acc = 0.f;
#pragma unroll
            for (int i8 = 0; i8 < 16; ++i8) {
                s16x8 yw = ywr[i8];
                f32x4 s0 = *(const f32x4*)&sp[i8 * 8];
                f32x4 s1 = *(const f32x4*)&sp[i8 * 8 + 4];
                f32x4 w0 = *(const f32x4*)&wap[i8 * 8];
                f32x4 w1 = *(const f32x4*)&wap[i8 * 8 + 4];
#pragma unroll
                for (int j = 0; j < 4; ++j)
                    acc += ftanh(b2f((unsigned short)yw[j]) + s0[j]) * w0[j];
#pragma unroll
                for (int j = 0; j < 4; ++j)
                    acc += ftanh(b2f((unsigned short)yw[4 + j]) + s1[j]) * w1[j];
            }
            part[tid] = acc;
        }
        __syncthreads();
        if (tid < T_SZ)
            lg[tid] = __expf(part[tid * 4] + part[tid * 4 + 1]
                           + part[tid * 4 + 2] + part[tid * 4 + 3] - mm);
        __syncthreads();
        if (tid < 64) lgp[tid] = pk2(lg[2 * tid], lg[2 * tid + 1]);
        __syncthreads();
        // ---- phase 3: a[n] via dot2 over tp-pairs ----
        {
            float av = 0.f, su = 0.f;
#pragma unroll 8
            for (int i = 0; i < 64; ++i) {
                unsigned l2 = lgp[i];
                unsigned y2 = ytp[i][tid];
                av = dot2bf(l2, y2, av);
                su = dot2bf(l2, ONE2, su);
            }
            part[tid] = av / su;
        }
        __syncthreads();
        if (tid < 256) xa16[tid] = pk2(part[2 * tid], part[2 * tid + 1]);
        __syncthreads();
        // ---- phase 4: gates (6-fam double-buffered weight loads) + combine ----
        {
            float aR = 0.f, aZ = 0.f, aGN = 0.f, aHN = 0.f;
            u32x4 wa0, wa1, wa2, wa3, wa4, wa5;
            u32x4 wb0, wb1, wb2, wb3, wb4, wb5;
            wa0 = wgp4[0];            wa1 = wgp4[1L << 15];
            wa2 = wgp4[2L << 15];     wa3 = wgp4[3L << 15];
            wa4 = wgp4[4L << 15];     wa5 = wgp4[5L << 15];
#pragma unroll 2
            for (int k2 = 0; k2 < 32; ++k2) {
                const int kA = 2 * k2, kB = 2 * k2 + 1;
                const long koB = (long)kB * 512;
                wb0 = wgp4[koB];             wb1 = wgp4[koB + (1L << 15)];
                wb2 = wgp4[koB + (2L << 15)]; wb3 = wgp4[koB + (3L << 15)];
                wb4 = wgp4[koB + (4L << 15)]; wb5 = wgp4[koB + (5L << 15)];
                {
                    u32x4 xa = xa4[kA], xr = xr4[kA];
#pragma unroll
                    for (int j = 0; j < 4; ++j) {
                        aR  = dot2bf(wa0[j], xa[j], aR);
                        aZ  = dot2bf(wa1[j], xa[j], aZ);
                        aGN = dot2bf(wa2[j], xa[j], aGN);
                        aR  = dot2bf(wa3[j], xr[j], aR);
                        aZ  = dot2bf(wa4[j], xr[j], aZ);
                        aHN = dot2bf(wa5[j], xr[j], aHN);
                    }
                }
                if (k2 < 31) {
                    const long koA = (long)(kB + 1) * 512;
                    wa0 = wgp4[koA];              wa1 = wgp4[koA + (1L << 15)];
                    wa2 = wgp4[koA + (2L << 15)]; wa3 = wgp4[koA + (3L << 15)];
                    wa4 = wgp4[koA + (4L << 15)]; wa5 = wgp4[koA + (5L << 15)];
                }
                {
                    u32x4 xa = xa4[kB], xr = xr4[kB];
#pragma unroll
                    for (int j = 0; j < 4; ++j) {
                        aR  = dot2bf(wb0[j], xa[j], aR);
                        aZ  = dot2bf(wb1[j], xa[j], aZ);
                        aGN = dot2bf(wb2[j], xa[j], aGN);
                        aR  = dot2bf(wb3[j], xr[j], aR);
                        aZ  = dot2bf(wb4[j], xr[j], aZ);
                        aHN = dot2bf(wb5[j], xr[j], aHN);
                    }
                }
            }
            const unsigned short* og = OHGI_bt + ((long)b * T_SZ + t) * G3;
            float rg = fsigmoid(aR + b2f(og[tid]) + m_bhh[tid]);
            float zg = fsigmoid(aZ + b2f(og[ND + tid]) + m_bhh[ND + tid]);
            float ng = ftanh(aGN + b2f(og[2 * ND + tid])
                             + rg * (aHN + m_bhh[2 * ND + tid]));
            float rp = xr32[tid];
            float rn = (1.0f - zg) * ng + zg * rp;
            bool mk = hyp[b * T_SZ + t] != 0;
            float v = mk ? rn : rp;
            __syncthreads();                 // all GEMV reads of old r done
            xr32[tid] = v;
            part[tid] = v;
        }
        __syncthreads();
        if (tid < 256) xr16[tid] = pk2(part[2 * tid], part[2 * tid + 1]);
        __syncthreads();
    }
    r32[(long)b * ND + tid] = xr32[tid];
}

// ---------------- prep / misc ----------------
__global__ void prep_idx(const int* __restrict__ prem, const int* __restrict__ hyp,
                         int* __restrict__ idx_p, int* __restrict__ idx_h)
{
    int i = blockIdx.x * blockDim.x + threadIdx.x;
    if (i < B_SZ * T_SZ) {
        int t = i / B_SZ, b = i % B_SZ;
        idx_p[i] = prem[b * T_SZ + t];
        idx_h[i] = hyp[b * T_SZ + t];
    }
}

__global__ void conv_w(const float* __restrict__ in, unsigned short* __restrict__ out,
                       int N, int K, int Kpad, int ldIn, int colOff)
{
    long i = (long)blockIdx.x * blockDim.x + threadIdx.x;
    if (i >= (long)N * Kpad) return;
    int n = (int)(i / Kpad), k = (int)(i % Kpad);
    float v = (k < K) ? in[(long)n * ldIn + k + colOff] : 0.0f;
    out[i] = f2b(v);
}

__global__ void conv_wT(const float* __restrict__ in, unsigned short* __restrict__ out,
                        int N, int K, int Kpad, int ldIn)
{
    long i = (long)blockIdx.x * blockDim.x + threadIdx.x;
    if (i >= (long)N * Kpad) return;
    int n = (int)(i / Kpad), k = (int)(i % Kpad);
    float v = (k < K) ? in[(long)k * ldIn + n] : 0.0f;
    out[i] = f2b(v);
}

// Ws[k8][n][j] = W_r[k8*8+j][n]
__global__ void pack_ws(const float* __restrict__ Wr, unsigned short* __restrict__ out)
{
    long i = (long)blockIdx.x * blockDim.x + threadIdx.x;
    if (i >= 64L * 512 * 8) return;
    int k8 = (int)(i >> 12), n = (int)((i >> 3) & 511), j = (int)(i & 7);
    out[i] = f2b(Wr[(long)(k8 * 8 + j) * ND + n]);
}

// Wg[fam][k8][n][j]: fam 0..2 a-side (m_Wih cols 0..511), fam 3..5 r-side (m_Whh)
__global__ void pack_wg(const float* __restrict__ mWih, const float* __restrict__ mWhh,
                        unsigned short* __restrict__ out)
{
    long i = (long)blockIdx.x * blockDim.x + threadIdx.x;
    if (i >= 6L * 64 * 512 * 8) return;
    int fam = (int)(i >> 18);
    long rem = i & 262143;
    int k8 = (int)(rem >> 12), n = (int)((rem >> 3) & 511), j = (int)(rem & 7);
    int k = k8 * 8 + j;
    float v;
    if (fam < 3) v = mWih[(long)(fam * ND + n) * 1024 + k];
    else         v = mWhh[(long)((fam - 3) * ND + n) * ND + k];
    out[i] = f2b(v);
}

__global__ void zero_kernel(float* __restrict__ p, int n)
{
    int i = blockIdx.x * blockDim.x + threadIdx.x;
    if (i < n) p[i] = 0.0f;
}

__global__ void final_logits(const float* __restrict__ r, const float* __restrict__ outW,
                             const float* __restrict__ outb, float* __restrict__ out)
{
    int b = blockIdx.x;
    int lane = threadIdx.x;
    float a0 = 0.0f, a1 = 0.0f, a2 = 0.0f;
    for (int k = lane; k < ND; k += 64) {
        float rv = r[(long)b * ND + k];
        a0 += rv * outW[0 * ND + k];
        a1 += rv * outW[1 * ND + k];
        a2 += rv * outW[2 * ND + k];
    }
#pragma unroll
    for (int off = 32; off; off >>= 1) {
        a0 += __shfl_down(a0, off);
        a1 += __shfl_down(a1, off);
        a2 += __shfl_down(a2, off);
    }
    if (lane == 0) {
        float l0 = a0 + outb[0], l1 = a1 + outb[1], l2 = a2 + outb[2];
        float mx = fmaxf(l0, fmaxf(l1, l2));
        float se = expf(l0 - mx) + expf(l1 - mx) + expf(l2 - mx);
        float ls = mx + logf(se);
        out[b * 3 + 0] = l0 - ls;
        out[b * 3 + 1] = l1 - ls;
        out[b * 3 + 2] = l2 - ls;
    }
}

// ---------------- host ----------------
extern "C" void kernel_launch(void* const* d_in, const int* in_sizes, int n_in,
                              void* d_out, int out_size, void* d_ws, size_t ws_size,
                              hipStream_t stream)
{
    const int*   prem    = (const int*)d_in[0];
    const int*   hyp     = (const int*)d_in[1];
    const float* E       = (const float*)d_in[2];
    const float* p_Wih   = (const float*)d_in[3];
    const float* p_Whh   = (const float*)d_in[4];
    const float* p_bih   = (const float*)d_in[5];
    const float* p_bhh   = (const float*)d_in[6];
    const float* h_Wih   = (const float*)d_in[7];
    const float* h_Whh   = (const float*)d_in[8];
    const float* h_bih   = (const float*)d_in[9];
    const float* h_bhh   = (const float*)d_in[10];
    const float* m_Wih   = (const float*)d_in[11];
    const float* m_Whh   = (const float*)d_in[12];
    const float* m_bih   = (const float*)d_in[13];
    const float* m_bhh   = (const float*)d_in[14];
    const float* W_y     = (const float*)d_in[15];
    const float* W_h     = (const float*)d_in[16];
    const float* W_r     = (const float*)d_in[17];
    const float* W_alpha = (const float*)d_in[18];
    const float* out_W   = (const float*)d_in[19];
    const float* out_b   = (const float*)d_in[20];
    float* out = (float*)d_out;

    const int MB = T_SZ * B_SZ;  // 16384
    const int NFLAGS = NREP * NFID * FPAD;

    float* ws = (float*)d_ws;
    size_t off = 0;
    float* GI    = ws + off; off += (size_t)MB * G3;
    float* h32   = ws + off; off += (size_t)B_SZ * ND;
    float* r32   = ws + off; off += (size_t)B_SZ * ND;
    unsigned* flags = (unsigned*)(ws + off); off += NFLAGS;
    int* idx_p = (int*)(ws + off); off += (size_t)B_SZ * T_SZ;
    int* idx_h = (int*)(ws + off); off += (size_t)B_SZ * T_SZ;
    unsigned short* ub = (unsigned short*)(ws + off);
    size_t uoff = 0;
    unsigned short* o_p_bt = ub + uoff; uoff += (size_t)MB * ND;   // Y
    unsigned short* o_h_bt = ub + uoff; uoff += (size_t)MB * ND;
    unsigned short* Yw_bb  = ub + uoff; uoff += (size_t)MB * ND;
    unsigned short* OHWh_bt= ub + uoff; uoff += (size_t)MB * ND;
    unsigned short* OHGI_bt= ub + uoff; uoff += (size_t)MB * G3;
    unsigned short* h16a   = ub + uoff; uoff += (size_t)B_SZ * ND;
    unsigned short* h16b   = ub + uoff; uoff += (size_t)B_SZ * ND;
    unsigned short* pWih_b = ub + uoff; uoff += (size_t)G3 * 320;
    unsigned short* hWih_b = ub + uoff; uoff += (size_t)G3 * 320;
    unsigned short* pWhh_b = ub + uoff; uoff += (size_t)G3 * ND;
    unsigned short* hWhh_b = ub + uoff; uoff += (size_t)G3 * ND;
    unsigned short* mWihR  = ub + uoff; uoff += (size_t)G3 * ND;
    unsigned short* WyT_b  = ub + uoff; uoff += (size_t)ND * ND;
    unsigned short* WhT_b  = ub + uoff; uoff += (size_t)ND * ND;
    unsigned short* Ws_p   = ub + uoff; uoff += 64L * 512 * 8;
    unsigned short* Wg_p   = ub + uoff; uoff += 6L * 64 * 512 * 8;
    off += (uoff + 1) / 2;
    if (ws_size < off * sizeof(float)) return;

    auto cblk = [](long n) { return (int)((n + 255) / 256); };

    // ---- prep ----
    prep_idx<<<cblk(MB), 256, 0, stream>>>(prem, hyp, idx_p, idx_h);
    conv_w <<<cblk((long)G3 * 320), 256, 0, stream>>>(p_Wih, pWih_b, G3, EMBD, 320, EMBD, 0);
    conv_w <<<cblk((long)G3 * 320), 256, 0, stream>>>(h_Wih, hWih_b, G3, EMBD, 320, EMBD, 0);
    conv_w <<<cblk((long)G3 * ND), 256, 0, stream>>>(p_Whh, pWhh_b, G3, ND, ND, ND, 0);
    conv_w <<<cblk((long)G3 * ND), 256, 0, stream>>>(h_Whh, hWhh_b, G3, ND, ND, ND, 0);
    conv_w <<<cblk((long)G3 * ND), 256, 0, stream>>>(m_Wih, mWihR, G3, ND, ND, 2 * ND, ND);
    conv_wT<<<cblk((long)ND * ND), 256, 0, stream>>>(W_y, WyT_b, ND, ND, ND, ND);
    conv_wT<<<cblk((long)ND * ND), 256, 0, stream>>>(W_h, WhT_b, ND, ND, ND, ND);
    pack_ws<<<cblk(64L * 512 * 8), 256, 0, stream>>>(W_r, Ws_p);
    pack_wg<<<cblk(6L * 64 * 512 * 8), 256, 0, stream>>>(m_Wih, m_Whh, Wg_p);
    zero_kernel<<<cblk(B_SZ * ND), 256, 0, stream>>>(h32, B_SZ * ND);
    zero_kernel<<<cblk(B_SZ * ND / 2), 256, 0, stream>>>((float*)h16a, B_SZ * ND / 2);
    zero_kernel<<<cblk(NFLAGS), 256, 0, stream>>>((float*)flags, NFLAGS);

    // ---- premise ----
    {
        dim3 g(G3 / 64, MB / 64);
        mfma_gemm<float, false><<<g, 256, 0, stream>>>(E, idx_p, pWih_b, p_bih, GI,
                                                       MB, G3, EMBD, EMBD, 320, G3);
    }
    gru_chain<<<GRU_NB, 256, 0, stream>>>(pWhh_b, GI, p_bhh, prem, h32, h16a, h16b,
                                          o_p_bt, flags, FB_GRUP);

    // ---- hypothesis ----
    {
        dim3 g(G3 / 64, MB / 64);
        mfma_gemm<float, false><<<g, 256, 0, stream>>>(E, idx_h, hWih_b, h_bih, GI,
                                                       MB, G3, EMBD, EMBD, 320, G3);
    }
    gru_chain<<<GRU_NB, 256, 0, stream>>>(hWhh_b, GI, h_bhh, hyp, h32, h16a, h16b,
                                          o_h_bt, flags, FB_GRUH);

    // ---- attention precompute (all [b][t]-row layouts) ----
    {
        dim3 g(ND / 64, MB / 64);
        mfma_gemm<unsigned short, true><<<g, 256, 0, stream>>>(o_p_bt, nullptr, WyT_b, nullptr,
                                                               Yw_bb, MB, ND, ND, ND, ND, ND);
        mfma_gemm<unsigned short, true><<<g, 256, 0, stream>>>(o_h_bt, nullptr, WhT_b, nullptr,
                                                               OHWh_bt, MB, ND, ND, ND, ND, ND);
        dim3 g2(G3 / 64, MB / 64);
        mfma_gemm<unsigned short, true><<<g2, 256, 0, stream>>>(o_h_bt, nullptr, mWihR, m_bih,
                                                                OHGI_bt, MB, G3, ND, ND, ND, G3);
    }

    // ---- match: sync-free, one block per batch element ----
    match_pb<<<B_SZ, 512, 0, stream>>>(Ws_p, Wg_p, OHWh_bt, OHGI_bt, m_bhh, W_alpha,
                                       Yw_bb, o_p_bt, prem, hyp, r32);

    final_logits<<<B_SZ, 64, 0, stream>>>(r32, out_W, out_b, out);
}

// Round 19
// 6661.530 us; speedup vs baseline: 1.6313x; 1.6313x over previous
//
#include <hip/hip_runtime.h>
#include <math.h>

#define B_SZ 128
#define T_SZ 128
#define EMBD 300
#define ND 512
#define G3 1536
#define FPAD 32    // flag padding stride (u32s) = 128 B
#define NFID 128   // flag ids per replica
#define NREP 8     // flag replicas
#define SPAD 132   // padded q-segment stride (floats): bank shift 4 per q

typedef short s16x8 __attribute__((ext_vector_type(8)));
typedef float f32x4 __attribute__((ext_vector_type(4)));
typedef unsigned u32x4 __attribute__((ext_vector_type(4)));
typedef unsigned long long u64;

__device__ __forceinline__ unsigned short f2b(float x) {
    unsigned u = __float_as_uint(x);
    unsigned r = (u + 0x7fff + ((u >> 16) & 1)) >> 16;  // RNE
    return (unsigned short)r;
}
__device__ __forceinline__ float b2f(unsigned short v) {
    return __uint_as_float(((unsigned)v) << 16);
}
__device__ __forceinline__ unsigned pk2(float lo, float hi) {
    return (unsigned)f2b(lo) | ((unsigned)f2b(hi) << 16);
}
__device__ __forceinline__ float fsigmoid(float x) { return 1.0f / (1.0f + __expf(-x)); }
__device__ __forceinline__ float ftanh(float x) { return 1.0f - 2.0f / (__expf(2.0f * x) + 1.0f); }

// packed bf16 dot2: c += a.lo*b.lo + a.hi*b.hi (single VOP3P instruction)
__device__ __forceinline__ float dot2bf(unsigned a, unsigned b, float c) {
    asm("v_dot2_f32_bf16 %0, %1, %2, %0" : "+v"(c) : "v"(a), "v"(b));
    return c;
}

__device__ __forceinline__ f32x4 mfma16(s16x8 a, s16x8 b, f32x4 c) {
    return __builtin_amdgcn_mfma_f32_16x16x32_bf16(a, b, c, 0, 0, 0);
}

// ---- coherent (LLC-point, fence-free) helpers (GRU chains only) ----
__device__ __forceinline__ u64 cld64(const void* p) {
    return __hip_atomic_load((const u64*)p, __ATOMIC_RELAXED, __HIP_MEMORY_SCOPE_AGENT);
}
__device__ __forceinline__ void cst64(void* p, u64 v) {
    __hip_atomic_store((u64*)p, v, __ATOMIC_RELAXED, __HIP_MEMORY_SCOPE_AGENT);
}
__device__ __forceinline__ unsigned cld32(const void* p) {
    return __hip_atomic_load((const unsigned*)p, __ATOMIC_RELAXED, __HIP_MEMORY_SCOPE_AGENT);
}
__device__ __forceinline__ void cst32(void* p, unsigned v) {
    __hip_atomic_store((unsigned*)p, v, __ATOMIC_RELAXED, __HIP_MEMORY_SCOPE_AGENT);
}
__device__ __forceinline__ s16x8 cld_frag(const unsigned short* p) {
    union { u64 q[2]; s16x8 v; } u;
    u.q[0] = cld64(p);
    u.q[1] = cld64(p + 4);
    return u.v;
}

// ---- replicated-flag grid barrier (GRU chains) ----
__device__ __forceinline__ void postflag(unsigned* flags, int base, int id, unsigned ep)
{
    if (threadIdx.x < NREP)
        cst32(&flags[((long)threadIdx.x * NFID + base + id) * FPAD], ep);
}
__device__ __forceinline__ void waitflags(const unsigned* flags, int base, int n,
                                          unsigned ep, int rep)
{
    const unsigned* fr = flags + (long)rep * NFID * FPAD;
    if (threadIdx.x < 64) {
#pragma unroll 1
        for (int i = threadIdx.x; i < n; i += 64)
            while (cld32(&fr[(long)(base + i) * FPAD]) < ep)
                __builtin_amdgcn_s_sleep(2);
    }
    __syncthreads();
}
__device__ __forceinline__ void fbar(unsigned* flags, int base, int nb, unsigned ep)
{
    __syncthreads();
    postflag(flags, base, blockIdx.x & 63, ep);
    waitflags(flags, base, nb, ep, blockIdx.x & 7);
}

#define FB_GRUP 0
#define FB_GRUH 64

// ---------------- generic MFMA GEMM (precompute only) ----------------
template<typename AT, bool OB>
__global__ __launch_bounds__(256)
void mfma_gemm(const AT* __restrict__ A, const int* __restrict__ idxA,
               const unsigned short* __restrict__ Wb, const float* __restrict__ bias,
               void* __restrict__ Cv,
               int M, int N, int K, int ldA, int Kpad, int ldC)
{
    __shared__ unsigned short As[64][40];
    __shared__ unsigned short Bs[64][40];
    const int tid = threadIdx.x;
    const int wv = tid >> 6, lane = tid & 63;
    const int wm = wv >> 1, wn = wv & 1;
    const int m0 = blockIdx.y * 64, n0 = blockIdx.x * 64;

    f32x4 acc[2][2] = {{{0.f,0.f,0.f,0.f},{0.f,0.f,0.f,0.f}},
                       {{0.f,0.f,0.f,0.f},{0.f,0.f,0.f,0.f}}};
    const int r_st = tid >> 2, k_st = (tid & 3) * 8;

    long arow = -1;
    {
        int gm = m0 + r_st;
        if (gm < M) arow = idxA ? (long)idxA[gm] : (long)gm;
    }

    const int kIters = (K + 31) / 32;
    for (int it = 0; it < kIters; ++it) {
        const int kg = it * 32 + k_st;
        {
            s16x8 pk = {0,0,0,0,0,0,0,0};
            if (arow >= 0) {
                if constexpr (sizeof(AT) == 2) {
                    if (kg + 8 <= K) {
                        pk = *(const s16x8*)((const unsigned short*)A + arow * (long)ldA + kg);
                    } else {
#pragma unroll
                        for (int j = 0; j < 8; ++j)
                            if (kg + j < K) pk[j] = (short)((const unsigned short*)A)[arow * (long)ldA + kg + j];
                    }
                } else {
                    if (kg + 8 <= K) {
                        const float* p = (const float*)A + arow * (long)ldA + kg;
                        f32x4 u0 = *(const f32x4*)p;
                        f32x4 u1 = *(const f32x4*)(p + 4);
#pragma unroll
                        for (int j = 0; j < 4; ++j) { pk[j] = (short)f2b(u0[j]); pk[4+j] = (short)f2b(u1[j]); }
                    } else {
#pragma unroll
                        for (int j = 0; j < 8; ++j) {
                            int kk = kg + j;
                            if (kk < K) pk[j] = (short)f2b(((const float*)A)[arow * (long)ldA + kk]);
                        }
                    }
                }
            }
            *(s16x8*)&As[r_st][k_st] = pk;
        }
        {
            int gn = n0 + r_st;
            s16x8 pk = {0,0,0,0,0,0,0,0};
            if (gn < N) pk = *(const s16x8*)&Wb[(long)gn * Kpad + kg];
            *(s16x8*)&Bs[r_st][k_st] = pk;
        }
        __syncthreads();
        {
            const int koff = (lane >> 4) * 8;
            s16x8 af[2], bfr[2];
#pragma unroll
            for (int f = 0; f < 2; ++f) {
                af[f]  = *(s16x8*)&As[wm * 32 + f * 16 + (lane & 15)][koff];
                bfr[f] = *(s16x8*)&Bs[wn * 32 + f * 16 + (lane & 15)][koff];
            }
#pragma unroll
            for (int fi = 0; fi < 2; ++fi)
#pragma unroll
                for (int fj = 0; fj < 2; ++fj)
                    acc[fi][fj] = mfma16(af[fi], bfr[fj], acc[fi][fj]);
        }
        __syncthreads();
    }
#pragma unroll
    for (int fi = 0; fi < 2; ++fi)
#pragma unroll
        for (int fj = 0; fj < 2; ++fj)
#pragma unroll
            for (int r = 0; r < 4; ++r) {
                int m = m0 + wm * 32 + fi * 16 + (lane >> 4) * 4 + r;
                int n = n0 + wn * 32 + fj * 16 + (lane & 15);
                if (m < M && n < N) {
                    float v = acc[fi][fj][r];
                    if (bias) v += bias[n];
                    if constexpr (OB) ((unsigned short*)Cv)[(long)m * ldC + n] = f2b(v);
                    else               ((float*)Cv)[(long)m * ldC + n] = v;
                }
            }
}

// ---------------- persistent GRU chain (unchanged) ----------------
#define GRU_NB 64
__global__ __launch_bounds__(256, 1)
void gru_chain(const unsigned short* __restrict__ Whh_b, const float* __restrict__ GI,
               const float* __restrict__ bhh, const int* __restrict__ toks,
               float* __restrict__ h32,
               unsigned short* __restrict__ h16a, unsigned short* __restrict__ h16b,
               unsigned short* __restrict__ o_bt,
               unsigned* __restrict__ flags, int fbase)
{
    __shared__ unsigned short wlds[3][16][512];   // 48 KB
    __shared__ unsigned short ht[64][20];
    const int tid = threadIdx.x;
    const int wv = tid >> 6, lane = tid & 63;
    const int dt = blockIdx.x & 31, bh = blockIdx.x >> 5;
    const int b0 = bh * 64;

    for (int s = 0; s < 12; ++s) {
        int slot = tid + s * 256;
        int g = slot >> 10, rem = slot & 1023, ks = rem >> 6, ln = rem & 63;
        int row = g * ND + dt * 16 + (ln & 15);
        int k = ks * 32 + (ln >> 4) * 8;
        *(s16x8*)&wlds[g][ks][ln * 8] = *(const s16x8*)&Whh_b[(long)row * ND + k];
    }
    __syncthreads();

    const int d = dt * 16 + (lane & 15);
    const int brow = b0 + wv * 16 + (lane >> 4) * 4;
    const long fhrd = ((long)(bh * 4 + wv) * 16) << 9;

    const int bl = tid & 63, dq = tid >> 6;
    const long fhwr = (((long)(bh * 4 + (bl >> 4)) * 16 + (dt >> 1)) << 9)
                    + (((((dt & 1) * 16 + dq * 4) >> 3) * 16 + (bl & 15)) * 8)
                    + (((dt & 1) * 16 + dq * 4) & 7);

    float hreg[4];
#pragma unroll
    for (int rr = 0; rr < 4; ++rr) hreg[rr] = h32[(long)(brow + rr) * ND + d];

    float o_run[4] = {0.f, 0.f, 0.f, 0.f};
    unsigned ep = 0;

    for (int t = 0; t < T_SZ; ++t) {
        const unsigned short* hin16 = (t & 1) ? h16b : h16a;
        unsigned short* hout16 = (t & 1) ? h16a : h16b;

        const float* git = GI + (long)t * (B_SZ * G3);
        float gi_r[4], gi_z[4], gi_n[4]; int mk[4];
#pragma unroll
        for (int rr = 0; rr < 4; ++rr) {
            int b = brow + rr;
            gi_r[rr] = git[(long)b * G3 + d];
            gi_z[rr] = git[(long)b * G3 + ND + d];
            gi_n[rr] = git[(long)b * G3 + 2 * ND + d];
            mk[rr]   = toks[b * T_SZ + t];
        }

        f32x4 acc0 = {0,0,0,0}, acc1 = {0,0,0,0}, acc2 = {0,0,0,0};
#pragma unroll
        for (int ks = 0; ks < 16; ++ks) {
            s16x8 a  = cld_frag(&hin16[fhrd + ((long)ks << 9) + lane * 8]);
            s16x8 br = *(s16x8*)&wlds[0][ks][lane * 8];
            s16x8 bz = *(s16x8*)&wlds[1][ks][lane * 8];
            s16x8 bn = *(s16x8*)&wlds[2][ks][lane * 8];
            acc0 = mfma16(a, br, acc0);
            acc1 = mfma16(a, bz, acc1);
            acc2 = mfma16(a, bn, acc2);
        }

#pragma unroll
        for (int rr = 0; rr < 4; ++rr) {
            int b = brow + rr;
            float rg = fsigmoid(gi_r[rr] + acc0[rr] + bhh[d]);
            float zg = fsigmoid(gi_z[rr] + acc1[rr] + bhh[ND + d]);
            float ng = ftanh(gi_n[rr] + rg * (acc2[rr] + bhh[2 * ND + d]));
            float hr = (1.0f - zg) * ng + zg * hreg[rr];
            bool m = mk[rr] != 0;
            float hn = m ? hr : hreg[rr];
            hreg[rr] = hn;
            ht[b - b0][lane & 15] = f2b(hn);
            if (t == T_SZ - 1) h32[(long)b * ND + d] = hn;
            o_run[rr] = (t == 0) ? hr : (m ? hr : o_run[rr]);
            o_bt[((long)b * T_SZ + t) * ND + d] = f2b(o_run[rr]);
        }
        __syncthreads();
        {
            u64 v = *(u64*)&ht[bl][dq * 4];
            cst64(&hout16[fhwr], v);
        }
        fbar(flags, fbase, GRU_NB, ++ep);
    }
}

// ---------------- sync-free per-batch match: r17 loads + padded LDS ----------------
// Ws: [64][512][8]  bf16; Wg: [6][64][512][8] fam: 0 R_a, 1 Z_a, 2 N_a, 3 R_r, 4 Z_r, 5 N_r
__global__ __launch_bounds__(512, 1)
void match_pb(const unsigned short* __restrict__ Ws,
              const unsigned short* __restrict__ Wg,
              const unsigned short* __restrict__ OHWh_bt,
              const unsigned short* __restrict__ OHGI_bt,
              const float* __restrict__ m_bhh, const float* __restrict__ Walpha,
              const unsigned short* __restrict__ Yw_bb,
              const unsigned short* __restrict__ Y_bb,
              const int* __restrict__ prem, const int* __restrict__ hyp,
              float* __restrict__ r32)
{
    __shared__ unsigned ytp[64][512];   // 128 KB: Y tp-pair packed [tp/2][n]
    __shared__ float sarr[4 * SPAD];    // padded q-segments (bank-shifted)
    __shared__ float wal[4 * SPAD];
    __shared__ float part[512];
    __shared__ float lg[T_SZ];
    __shared__ unsigned lgp[64];
    __shared__ unsigned xa16[256];      // a packed bf16 pairs
    __shared__ unsigned xr16[256];      // r packed bf16 pairs
    __shared__ float xr32[512];         // r f32 (recurrence blend)

    const int b = blockIdx.x;
    const int tid = threadIdx.x;   // 0..511
    const int tp = tid >> 2, q = tid & 3;

    // Y -> tp-pair packed LDS (once)
    for (int s = 0; s < 8; ++s) {
        int idx = s * 512 + tid;            // 4096 jobs: rp 0..63, ng 0..63
        int rp = idx >> 6, n0 = (idx & 63) * 8;
        s16x8 y0 = *(const s16x8*)&Y_bb[((long)b * T_SZ + 2 * rp) * ND + n0];
        s16x8 y1 = *(const s16x8*)&Y_bb[((long)b * T_SZ + 2 * rp + 1) * ND + n0];
#pragma unroll
        for (int j = 0; j < 8; ++j)
            ytp[rp][n0 + j] = (unsigned)(unsigned short)y0[j]
                            | ((unsigned)(unsigned short)y1[j] << 16);
    }
    // Yw slice -> registers (once)
    s16x8 ywr[16];
#pragma unroll
    for (int i8 = 0; i8 < 16; ++i8)
        ywr[i8] = *(const s16x8*)&Yw_bb[((long)b * T_SZ + tp) * ND + q * 128 + i8 * 8];

    wal[(tid >> 7) * SPAD + (tid & 127)] = Walpha[tid];
    xr32[tid] = 0.0f;
    if (tid < 256) xr16[tid] = 0u;
    float mm = 0.f;
    if (tid < T_SZ) mm = (prem[b * T_SZ + tid] != 0) ? 0.f : 1000.f;
    __syncthreads();

    const float* sp  = &sarr[q * SPAD];
    const float* wap = &wal[q * SPAD];
    const int sw = (tid >> 7) * SPAD + (tid & 127);    // padded write slot for n = tid
    const u32x4* wsp4 = (const u32x4*)((const unsigned*)Ws + tid * 4);   // stride 512 per k8
    const u32x4* wgp4 = (const u32x4*)((const unsigned*)Wg + tid * 4);
    const u32x4* xa4 = (const u32x4*)xa16;
    const u32x4* xr4 = (const u32x4*)xr16;
    const unsigned ONE2 = 0x3F803F80u;

    for (int t = 0; t < T_SZ; ++t) {
        // ---- phase 1: s[n] = r . W_r[:,n] + OHWh (16B weight loads, r17 loop) ----
        {
            float acc = 0.f;
#pragma unroll 4
            for (int k8 = 0; k8 < 64; ++k8) {
                u32x4 w = wsp4[(long)k8 * 512];
                u32x4 x = xr4[k8];
                acc = dot2bf(w[0], x[0], acc);
                acc = dot2bf(w[1], x[1], acc);
                acc = dot2bf(w[2], x[2], acc);
                acc = dot2bf(w[3], x[3], acc);
            }
            sarr[sw] = acc + b2f(OHWh_bt[((long)b * T_SZ + t) * ND + tid]);
        }
        __syncthreads();
        // ---- phase 2: logits (Yw regs, padded conflict-free LDS) ----
        {
            float acc = 0.f;
#pragma unroll
            for (int i8 = 0; i8 < 16; ++i8) {
                s16x8 yw = ywr[i8];
                f32x4 s0 = *(const f32x4*)&sp[i8 * 8];
                f32x4 s1 = *(const f32x4*)&sp[i8 * 8 + 4];
                f32x4 w0 = *(const f32x4*)&wap[i8 * 8];
                f32x4 w1 = *(const f32x4*)&wap[i8 * 8 + 4];
#pragma unroll
                for (int j = 0; j < 4; ++j)
                    acc += ftanh(b2f((unsigned short)yw[j]) + s0[j]) * w0[j];
#pragma unroll
                for (int j = 0; j < 4; ++j)
                    acc += ftanh(b2f((unsigned short)yw[4 + j]) + s1[j]) * w1[j];
            }
            part[tid] = acc;
        }
        __syncthreads();
        if (tid < T_SZ)
            lg[tid] = __expf(part[tid * 4] + part[tid * 4 + 1]
                           + part[tid * 4 + 2] + part[tid * 4 + 3] - mm);
        __syncthreads();
        if (tid < 64) lgp[tid] = pk2(lg[2 * tid], lg[2 * tid + 1]);
        __syncthreads();
        // ---- phase 3: a[n] via dot2 over tp-pairs ----
        {
            float av = 0.f, su = 0.f;
#pragma unroll 8
            for (int i = 0; i < 64; ++i) {
                unsigned l2 = lgp[i];
                unsigned y2 = ytp[i][tid];
                av = dot2bf(l2, y2, av);
                su = dot2bf(l2, ONE2, su);
            }
            part[tid] = av / su;
        }
        __syncthreads();
        if (tid < 256) xa16[tid] = pk2(part[2 * tid], part[2 * tid + 1]);
        __syncthreads();
        // ---- phase 4: gates via dot2 + 16B weight loads (r17 loop) + combine ----
        {
            float aR = 0.f, aZ = 0.f, aGN = 0.f, aHN = 0.f;
#pragma unroll 2
            for (int k8 = 0; k8 < 64; ++k8) {
                u32x4 xa = xa4[k8];
                u32x4 xr = xr4[k8];
                const long ko = (long)k8 * 512;
                u32x4 wRa = wgp4[ko];
                u32x4 wZa = wgp4[ko + (1L << 15)];
                u32x4 wNa = wgp4[ko + (2L << 15)];
                u32x4 wRr = wgp4[ko + (3L << 15)];
                u32x4 wZr = wgp4[ko + (4L << 15)];
                u32x4 wNr = wgp4[ko + (5L << 15)];
#pragma unroll
                for (int j = 0; j < 4; ++j) {
                    aR  = dot2bf(wRa[j], xa[j], aR);
                    aZ  = dot2bf(wZa[j], xa[j], aZ);
                    aGN = dot2bf(wNa[j], xa[j], aGN);
                    aR  = dot2bf(wRr[j], xr[j], aR);
                    aZ  = dot2bf(wZr[j], xr[j], aZ);
                    aHN = dot2bf(wNr[j], xr[j], aHN);
                }
            }
            const unsigned short* og = OHGI_bt + ((long)b * T_SZ + t) * G3;
            float rg = fsigmoid(aR + b2f(og[tid]) + m_bhh[tid]);
            float zg = fsigmoid(aZ + b2f(og[ND + tid]) + m_bhh[ND + tid]);
            float ng = ftanh(aGN + b2f(og[2 * ND + tid])
                             + rg * (aHN + m_bhh[2 * ND + tid]));
            float rp = xr32[tid];
            float rn = (1.0f - zg) * ng + zg * rp;
            bool mk = hyp[b * T_SZ + t] != 0;
            float v = mk ? rn : rp;
            __syncthreads();                 // all GEMV reads of old r done
            xr32[tid] = v;
            part[tid] = v;
        }
        __syncthreads();
        if (tid < 256) xr16[tid] = pk2(part[2 * tid], part[2 * tid + 1]);
        __syncthreads();
    }
    r32[(long)b * ND + tid] = xr32[tid];
}

// ---------------- prep / misc ----------------
__global__ void prep_idx(const int* __restrict__ prem, const int* __restrict__ hyp,
                         int* __restrict__ idx_p, int* __restrict__ idx_h)
{
    int i = blockIdx.x * blockDim.x + threadIdx.x;
    if (i < B_SZ * T_SZ) {
        int t = i / B_SZ, b = i % B_SZ;
        idx_p[i] = prem[b * T_SZ + t];
        idx_h[i] = hyp[b * T_SZ + t];
    }
}

__global__ void conv_w(const float* __restrict__ in, unsigned short* __restrict__ out,
                       int N, int K, int Kpad, int ldIn, int colOff)
{
    long i = (long)blockIdx.x * blockDim.x + threadIdx.x;
    if (i >= (long)N * Kpad) return;
    int n = (int)(i / Kpad), k = (int)(i % Kpad);
    float v = (k < K) ? in[(long)n * ldIn + k + colOff] : 0.0f;
    out[i] = f2b(v);
}

__global__ void conv_wT(const float* __restrict__ in, unsigned short* __restrict__ out,
                        int N, int K, int Kpad, int ldIn)
{
    long i = (long)blockIdx.x * blockDim.x + threadIdx.x;
    if (i >= (long)N * Kpad) return;
    int n = (int)(i / Kpad), k = (int)(i % Kpad);
    float v = (k < K) ? in[(long)k * ldIn + n] : 0.0f;
    out[i] = f2b(v);
}

// Ws[k8][n][j] = W_r[k8*8+j][n]
__global__ void pack_ws(const float* __restrict__ Wr, unsigned short* __restrict__ out)
{
    long i = (long)blockIdx.x * blockDim.x + threadIdx.x;
    if (i >= 64L * 512 * 8) return;
    int k8 = (int)(i >> 12), n = (int)((i >> 3) & 511), j = (int)(i & 7);
    out[i] = f2b(Wr[(long)(k8 * 8 + j) * ND + n]);
}

// Wg[fam][k8][n][j]: fam 0..2 a-side (m_Wih cols 0..511), fam 3..5 r-side (m_Whh)
__global__ void pack_wg(const float* __restrict__ mWih, const float* __restrict__ mWhh,
                        unsigned short* __restrict__ out)
{
    long i = (long)blockIdx.x * blockDim.x + threadIdx.x;
    if (i >= 6L * 64 * 512 * 8) return;
    int fam = (int)(i >> 18);
    long rem = i & 262143;
    int k8 = (int)(rem >> 12), n = (int)((rem >> 3) & 511), j = (int)(rem & 7);
    int k = k8 * 8 + j;
    float v;
    if (fam < 3) v = mWih[(long)(fam * ND + n) * 1024 + k];
    else         v = mWhh[(long)((fam - 3) * ND + n) * ND + k];
    out[i] = f2b(v);
}

__global__ void zero_kernel(float* __restrict__ p, int n)
{
    int i = blockIdx.x * blockDim.x + threadIdx.x;
    if (i < n) p[i] = 0.0f;
}

__global__ void final_logits(const float* __restrict__ r, const float* __restrict__ outW,
                             const float* __restrict__ outb, float* __restrict__ out)
{
    int b = blockIdx.x;
    int lane = threadIdx.x;
    float a0 = 0.0f, a1 = 0.0f, a2 = 0.0f;
    for (int k = lane; k < ND; k += 64) {
        float rv = r[(long)b * ND + k];
        a0 += rv * outW[0 * ND + k];
        a1 += rv * outW[1 * ND + k];
        a2 += rv * outW[2 * ND + k];
    }
#pragma unroll
    for (int off = 32; off; off >>= 1) {
        a0 += __shfl_down(a0, off);
        a1 += __shfl_down(a1, off);
        a2 += __shfl_down(a2, off);
    }
    if (lane == 0) {
        float l0 = a0 + outb[0], l1 = a1 + outb[1], l2 = a2 + outb[2];
        float mx = fmaxf(l0, fmaxf(l1, l2));
        float se = expf(l0 - mx) + expf(l1 - mx) + expf(l2 - mx);
        float ls = mx + logf(se);
        out[b * 3 + 0] = l0 - ls;
        out[b * 3 + 1] = l1 - ls;
        out[b * 3 + 2] = l2 - ls;
    }
}

// ---------------- host ----------------
extern "C" void kernel_launch(void* const* d_in, const int* in_sizes, int n_in,
                              void* d_out, int out_size, void* d_ws, size_t ws_size,
                              hipStream_t stream)
{
    const int*   prem    = (const int*)d_in[0];
    const int*   hyp     = (const int*)d_in[1];
    const float* E       = (const float*)d_in[2];
    const float* p_Wih   = (const float*)d_in[3];
    const float* p_Whh   = (const float*)d_in[4];
    const float* p_bih   = (const float*)d_in[5];
    const float* p_bhh   = (const float*)d_in[6];
    const float* h_Wih   = (const float*)d_in[7];
    const float* h_Whh   = (const float*)d_in[8];
    const float* h_bih   = (const float*)d_in[9];
    const float* h_bhh   = (const float*)d_in[10];
    const float* m_Wih   = (const float*)d_in[11];
    const float* m_Whh   = (const float*)d_in[12];
    const float* m_bih   = (const float*)d_in[13];
    const float* m_bhh   = (const float*)d_in[14];
    const float* W_y     = (const float*)d_in[15];
    const float* W_h     = (const float*)d_in[16];
    const float* W_r     = (const float*)d_in[17];
    const float* W_alpha = (const float*)d_in[18];
    const float* out_W   = (const float*)d_in[19];
    const float* out_b   = (const float*)d_in[20];
    float* out = (float*)d_out;

    const int MB = T_SZ * B_SZ;  // 16384
    const int NFLAGS = NREP * NFID * FPAD;

    float* ws = (float*)d_ws;
    size_t off = 0;
    float* GI    = ws + off; off += (size_t)MB * G3;
    float* h32   = ws + off; off += (size_t)B_SZ * ND;
    float* r32   = ws + off; off += (size_t)B_SZ * ND;
    unsigned* flags = (unsigned*)(ws + off); off += NFLAGS;
    int* idx_p = (int*)(ws + off); off += (size_t)B_SZ * T_SZ;
    int* idx_h = (int*)(ws + off); off += (size_t)B_SZ * T_SZ;
    unsigned short* ub = (unsigned short*)(ws + off);
    size_t uoff = 0;
    unsigned short* o_p_bt = ub + uoff; uoff += (size_t)MB * ND;   // Y
    unsigned short* o_h_bt = ub + uoff; uoff += (size_t)MB * ND;
    unsigned short* Yw_bb  = ub + uoff; uoff += (size_t)MB * ND;
    unsigned short* OHWh_bt= ub + uoff; uoff += (size_t)MB * ND;
    unsigned short* OHGI_bt= ub + uoff; uoff += (size_t)MB * G3;
    unsigned short* h16a   = ub + uoff; uoff += (size_t)B_SZ * ND;
    unsigned short* h16b   = ub + uoff; uoff += (size_t)B_SZ * ND;
    unsigned short* pWih_b = ub + uoff; uoff += (size_t)G3 * 320;
    unsigned short* hWih_b = ub + uoff; uoff += (size_t)G3 * 320;
    unsigned short* pWhh_b = ub + uoff; uoff += (size_t)G3 * ND;
    unsigned short* hWhh_b = ub + uoff; uoff += (size_t)G3 * ND;
    unsigned short* mWihR  = ub + uoff; uoff += (size_t)G3 * ND;
    unsigned short* WyT_b  = ub + uoff; uoff += (size_t)ND * ND;
    unsigned short* WhT_b  = ub + uoff; uoff += (size_t)ND * ND;
    unsigned short* Ws_p   = ub + uoff; uoff += 64L * 512 * 8;
    unsigned short* Wg_p   = ub + uoff; uoff += 6L * 64 * 512 * 8;
    off += (uoff + 1) / 2;
    if (ws_size < off * sizeof(float)) return;

    auto cblk = [](long n) { return (int)((n + 255) / 256); };

    // ---- prep ----
    prep_idx<<<cblk(MB), 256, 0, stream>>>(prem, hyp, idx_p, idx_h);
    conv_w <<<cblk((long)G3 * 320), 256, 0, stream>>>(p_Wih, pWih_b, G3, EMBD, 320, EMBD, 0);
    conv_w <<<cblk((long)G3 * 320), 256, 0, stream>>>(h_Wih, hWih_b, G3, EMBD, 320, EMBD, 0);
    conv_w <<<cblk((long)G3 * ND), 256, 0, stream>>>(p_Whh, pWhh_b, G3, ND, ND, ND, 0);
    conv_w <<<cblk((long)G3 * ND), 256, 0, stream>>>(h_Whh, hWhh_b, G3, ND, ND, ND, 0);
    conv_w <<<cblk((long)G3 * ND), 256, 0, stream>>>(m_Wih, mWihR, G3, ND, ND, 2 * ND, ND);
    conv_wT<<<cblk((long)ND * ND), 256, 0, stream>>>(W_y, WyT_b, ND, ND, ND, ND);
    conv_wT<<<cblk((long)ND * ND), 256, 0, stream>>>(W_h, WhT_b, ND, ND, ND, ND);
    pack_ws<<<cblk(64L * 512 * 8), 256, 0, stream>>>(W_r, Ws_p);
    pack_wg<<<cblk(6L * 64 * 512 * 8), 256, 0, stream>>>(m_Wih, m_Whh, Wg_p);
    zero_kernel<<<cblk(B_SZ * ND), 256, 0, stream>>>(h32, B_SZ * ND);
    zero_kernel<<<cblk(B_SZ * ND / 2), 256, 0, stream>>>((float*)h16a, B_SZ * ND / 2);
    zero_kernel<<<cblk(NFLAGS), 256, 0, stream>>>((float*)flags, NFLAGS);

    // ---- premise ----
    {
        dim3 g(G3 / 64, MB / 64);
        mfma_gemm<float, false><<<g, 256, 0, stream>>>(E, idx_p, pWih_b, p_bih, GI,
                                                       MB, G3, EMBD, EMBD, 320, G3);
    }
    gru_chain<<<GRU_NB, 256, 0, stream>>>(pWhh_b, GI, p_bhh, prem, h32, h16a, h16b,
                                          o_p_bt, flags, FB_GRUP);

    // ---- hypothesis ----
    {
        dim3 g(G3 / 64, MB / 64);
        mfma_gemm<float, false><<<g, 256, 0, stream>>>(E, idx_h, hWih_b, h_bih, GI,
                                                       MB, G3, EMBD, EMBD, 320, G3);
    }
    gru_chain<<<GRU_NB, 256, 0, stream>>>(hWhh_b, GI, h_bhh, hyp, h32, h16a, h16b,
                                          o_h_bt, flags, FB_GRUH);

    // ---- attention precompute (all [b][t]-row layouts) ----
    {
        dim3 g(ND / 64, MB / 64);
        mfma_gemm<unsigned short, true><<<g, 256, 0, stream>>>(o_p_bt, nullptr, WyT_b, nullptr,
                                                               Yw_bb, MB, ND, ND, ND, ND, ND);
        mfma_gemm<unsigned short, true><<<g, 256, 0, stream>>>(o_h_bt, nullptr, WhT_b, nullptr,
                                                               OHWh_bt, MB, ND, ND, ND, ND, ND);
        dim3 g2(G3 / 64, MB / 64);
        mfma_gemm<unsigned short, true><<<g2, 256, 0, stream>>>(o_h_bt, nullptr, mWihR, m_bih,
                                                                OHGI_bt, MB, G3, ND, ND, ND, G3);
    }

    // ---- match: sync-free, one block per batch element ----
    match_pb<<<B_SZ, 512, 0, stream>>>(Ws_p, Wg_p, OHWh_bt, OHGI_bt, m_bhh, W_alpha,
                                       Yw_bb, o_p_bt, prem, hyp, r32);

    final_logits<<<B_SZ, 64, 0, stream>>>(r32, out_W, out_b, out);
}

// Round 20
// 6562.824 us; speedup vs baseline: 1.6558x; 1.0150x over previous
//
#include <hip/hip_runtime.h>
#include <math.h>

#define B_SZ 128
#define T_SZ 128
#define EMBD 300
#define ND 512
#define G3 1536
#define FPAD 32    // flag padding stride (u32s) = 128 B
#define NFID 128   // flag ids per replica
#define NREP 8     // flag replicas
#define SPAD 132   // padded q-segment stride (floats): bank shift 4 per q

typedef short s16x8 __attribute__((ext_vector_type(8)));
typedef float f32x4 __attribute__((ext_vector_type(4)));
typedef unsigned u32x4 __attribute__((ext_vector_type(4)));
typedef unsigned long long u64;

__device__ __forceinline__ unsigned short f2b(float x) {
    unsigned u = __float_as_uint(x);
    unsigned r = (u + 0x7fff + ((u >> 16) & 1)) >> 16;  // RNE
    return (unsigned short)r;
}
__device__ __forceinline__ float b2f(unsigned short v) {
    return __uint_as_float(((unsigned)v) << 16);
}
__device__ __forceinline__ unsigned pk2(float lo, float hi) {
    return (unsigned)f2b(lo) | ((unsigned)f2b(hi) << 16);
}
__device__ __forceinline__ float fsigmoid(float x) { return 1.0f / (1.0f + __expf(-x)); }
__device__ __forceinline__ float ftanh(float x) { return 1.0f - 2.0f / (__expf(2.0f * x) + 1.0f); }

// packed bf16 dot2: c += a.lo*b.lo + a.hi*b.hi (single VOP3P instruction)
__device__ __forceinline__ float dot2bf(unsigned a, unsigned b, float c) {
    asm("v_dot2_f32_bf16 %0, %1, %2, %0" : "+v"(c) : "v"(a), "v"(b));
    return c;
}

__device__ __forceinline__ f32x4 mfma16(s16x8 a, s16x8 b, f32x4 c) {
    return __builtin_amdgcn_mfma_f32_16x16x32_bf16(a, b, c, 0, 0, 0);
}

// ---- coherent (LLC-point, fence-free) helpers (GRU chains only) ----
__device__ __forceinline__ u64 cld64(const void* p) {
    return __hip_atomic_load((const u64*)p, __ATOMIC_RELAXED, __HIP_MEMORY_SCOPE_AGENT);
}
__device__ __forceinline__ void cst64(void* p, u64 v) {
    __hip_atomic_store((u64*)p, v, __ATOMIC_RELAXED, __HIP_MEMORY_SCOPE_AGENT);
}
__device__ __forceinline__ unsigned cld32(const void* p) {
    return __hip_atomic_load((const unsigned*)p, __ATOMIC_RELAXED, __HIP_MEMORY_SCOPE_AGENT);
}
__device__ __forceinline__ void cst32(void* p, unsigned v) {
    __hip_atomic_store((unsigned*)p, v, __ATOMIC_RELAXED, __HIP_MEMORY_SCOPE_AGENT);
}
__device__ __forceinline__ s16x8 cld_frag(const unsigned short* p) {
    union { u64 q[2]; s16x8 v; } u;
    u.q[0] = cld64(p);
    u.q[1] = cld64(p + 4);
    return u.v;
}

// ---- replicated-flag grid barrier (GRU chains) ----
__device__ __forceinline__ void postflag(unsigned* flags, int base, int id, unsigned ep)
{
    if (threadIdx.x < NREP)
        cst32(&flags[((long)threadIdx.x * NFID + base + id) * FPAD], ep);
}
__device__ __forceinline__ void waitflags(const unsigned* flags, int base, int n,
                                          unsigned ep, int rep)
{
    const unsigned* fr = flags + (long)rep * NFID * FPAD;
    if (threadIdx.x < 64) {
#pragma unroll 1
        for (int i = threadIdx.x; i < n; i += 64)
            while (cld32(&fr[(long)(base + i) * FPAD]) < ep)
                __builtin_amdgcn_s_sleep(2);
    }
    __syncthreads();
}
__device__ __forceinline__ void fbar(unsigned* flags, int base, int nb, unsigned ep)
{
    __syncthreads();
    postflag(flags, base, blockIdx.x & 63, ep);
    waitflags(flags, base, nb, ep, blockIdx.x & 7);
}

#define FB_GRUP 0
#define FB_GRUH 64

// ---------------- generic MFMA GEMM (precompute only) ----------------
template<typename AT, bool OB>
__global__ __launch_bounds__(256)
void mfma_gemm(const AT* __restrict__ A, const int* __restrict__ idxA,
               const unsigned short* __restrict__ Wb, const float* __restrict__ bias,
               void* __restrict__ Cv,
               int M, int N, int K, int ldA, int Kpad, int ldC)
{
    __shared__ unsigned short As[64][40];
    __shared__ unsigned short Bs[64][40];
    const int tid = threadIdx.x;
    const int wv = tid >> 6, lane = tid & 63;
    const int wm = wv >> 1, wn = wv & 1;
    const int m0 = blockIdx.y * 64, n0 = blockIdx.x * 64;

    f32x4 acc[2][2] = {{{0.f,0.f,0.f,0.f},{0.f,0.f,0.f,0.f}},
                       {{0.f,0.f,0.f,0.f},{0.f,0.f,0.f,0.f}}};
    const int r_st = tid >> 2, k_st = (tid & 3) * 8;

    long arow = -1;
    {
        int gm = m0 + r_st;
        if (gm < M) arow = idxA ? (long)idxA[gm] : (long)gm;
    }

    const int kIters = (K + 31) / 32;
    for (int it = 0; it < kIters; ++it) {
        const int kg = it * 32 + k_st;
        {
            s16x8 pk = {0,0,0,0,0,0,0,0};
            if (arow >= 0) {
                if constexpr (sizeof(AT) == 2) {
                    if (kg + 8 <= K) {
                        pk = *(const s16x8*)((const unsigned short*)A + arow * (long)ldA + kg);
                    } else {
#pragma unroll
                        for (int j = 0; j < 8; ++j)
                            if (kg + j < K) pk[j] = (short)((const unsigned short*)A)[arow * (long)ldA + kg + j];
                    }
                } else {
                    if (kg + 8 <= K) {
                        const float* p = (const float*)A + arow * (long)ldA + kg;
                        f32x4 u0 = *(const f32x4*)p;
                        f32x4 u1 = *(const f32x4*)(p + 4);
#pragma unroll
                        for (int j = 0; j < 4; ++j) { pk[j] = (short)f2b(u0[j]); pk[4+j] = (short)f2b(u1[j]); }
                    } else {
#pragma unroll
                        for (int j = 0; j < 8; ++j) {
                            int kk = kg + j;
                            if (kk < K) pk[j] = (short)f2b(((const float*)A)[arow * (long)ldA + kk]);
                        }
                    }
                }
            }
            *(s16x8*)&As[r_st][k_st] = pk;
        }
        {
            int gn = n0 + r_st;
            s16x8 pk = {0,0,0,0,0,0,0,0};
            if (gn < N) pk = *(const s16x8*)&Wb[(long)gn * Kpad + kg];
            *(s16x8*)&Bs[r_st][k_st] = pk;
        }
        __syncthreads();
        {
            const int koff = (lane >> 4) * 8;
            s16x8 af[2], bfr[2];
#pragma unroll
            for (int f = 0; f < 2; ++f) {
                af[f]  = *(s16x8*)&As[wm * 32 + f * 16 + (lane & 15)][koff];
                bfr[f] = *(s16x8*)&Bs[wn * 32 + f * 16 + (lane & 15)][koff];
            }
#pragma unroll
            for (int fi = 0; fi < 2; ++fi)
#pragma unroll
                for (int fj = 0; fj < 2; ++fj)
                    acc[fi][fj] = mfma16(af[fi], bfr[fj], acc[fi][fj]);
        }
        __syncthreads();
    }
#pragma unroll
    for (int fi = 0; fi < 2; ++fi)
#pragma unroll
        for (int fj = 0; fj < 2; ++fj)
#pragma unroll
            for (int r = 0; r < 4; ++r) {
                int m = m0 + wm * 32 + fi * 16 + (lane >> 4) * 4 + r;
                int n = n0 + wn * 32 + fj * 16 + (lane & 15);
                if (m < M && n < N) {
                    float v = acc[fi][fj][r];
                    if (bias) v += bias[n];
                    if constexpr (OB) ((unsigned short*)Cv)[(long)m * ldC + n] = f2b(v);
                    else               ((float*)Cv)[(long)m * ldC + n] = v;
                }
            }
}

// ---------------- persistent GRU chain (unchanged) ----------------
#define GRU_NB 64
__global__ __launch_bounds__(256, 1)
void gru_chain(const unsigned short* __restrict__ Whh_b, const float* __restrict__ GI,
               const float* __restrict__ bhh, const int* __restrict__ toks,
               float* __restrict__ h32,
               unsigned short* __restrict__ h16a, unsigned short* __restrict__ h16b,
               unsigned short* __restrict__ o_bt,
               unsigned* __restrict__ flags, int fbase)
{
    __shared__ unsigned short wlds[3][16][512];   // 48 KB
    __shared__ unsigned short ht[64][20];
    const int tid = threadIdx.x;
    const int wv = tid >> 6, lane = tid & 63;
    const int dt = blockIdx.x & 31, bh = blockIdx.x >> 5;
    const int b0 = bh * 64;

    for (int s = 0; s < 12; ++s) {
        int slot = tid + s * 256;
        int g = slot >> 10, rem = slot & 1023, ks = rem >> 6, ln = rem & 63;
        int row = g * ND + dt * 16 + (ln & 15);
        int k = ks * 32 + (ln >> 4) * 8;
        *(s16x8*)&wlds[g][ks][ln * 8] = *(const s16x8*)&Whh_b[(long)row * ND + k];
    }
    __syncthreads();

    const int d = dt * 16 + (lane & 15);
    const int brow = b0 + wv * 16 + (lane >> 4) * 4;
    const long fhrd = ((long)(bh * 4 + wv) * 16) << 9;

    const int bl = tid & 63, dq = tid >> 6;
    const long fhwr = (((long)(bh * 4 + (bl >> 4)) * 16 + (dt >> 1)) << 9)
                    + (((((dt & 1) * 16 + dq * 4) >> 3) * 16 + (bl & 15)) * 8)
                    + (((dt & 1) * 16 + dq * 4) & 7);

    float hreg[4];
#pragma unroll
    for (int rr = 0; rr < 4; ++rr) hreg[rr] = h32[(long)(brow + rr) * ND + d];

    float o_run[4] = {0.f, 0.f, 0.f, 0.f};
    unsigned ep = 0;

    for (int t = 0; t < T_SZ; ++t) {
        const unsigned short* hin16 = (t & 1) ? h16b : h16a;
        unsigned short* hout16 = (t & 1) ? h16a : h16b;

        const float* git = GI + (long)t * (B_SZ * G3);
        float gi_r[4], gi_z[4], gi_n[4]; int mk[4];
#pragma unroll
        for (int rr = 0; rr < 4; ++rr) {
            int b = brow + rr;
            gi_r[rr] = git[(long)b * G3 + d];
            gi_z[rr] = git[(long)b * G3 + ND + d];
            gi_n[rr] = git[(long)b * G3 + 2 * ND + d];
            mk[rr]   = toks[b * T_SZ + t];
        }

        f32x4 acc0 = {0,0,0,0}, acc1 = {0,0,0,0}, acc2 = {0,0,0,0};
#pragma unroll
        for (int ks = 0; ks < 16; ++ks) {
            s16x8 a  = cld_frag(&hin16[fhrd + ((long)ks << 9) + lane * 8]);
            s16x8 br = *(s16x8*)&wlds[0][ks][lane * 8];
            s16x8 bz = *(s16x8*)&wlds[1][ks][lane * 8];
            s16x8 bn = *(s16x8*)&wlds[2][ks][lane * 8];
            acc0 = mfma16(a, br, acc0);
            acc1 = mfma16(a, bz, acc1);
            acc2 = mfma16(a, bn, acc2);
        }

#pragma unroll
        for (int rr = 0; rr < 4; ++rr) {
            int b = brow + rr;
            float rg = fsigmoid(gi_r[rr] + acc0[rr] + bhh[d]);
            float zg = fsigmoid(gi_z[rr] + acc1[rr] + bhh[ND + d]);
            float ng = ftanh(gi_n[rr] + rg * (acc2[rr] + bhh[2 * ND + d]));
            float hr = (1.0f - zg) * ng + zg * hreg[rr];
            bool m = mk[rr] != 0;
            float hn = m ? hr : hreg[rr];
            hreg[rr] = hn;
            ht[b - b0][lane & 15] = f2b(hn);
            if (t == T_SZ - 1) h32[(long)b * ND + d] = hn;
            o_run[rr] = (t == 0) ? hr : (m ? hr : o_run[rr]);
            o_bt[((long)b * T_SZ + t) * ND + d] = f2b(o_run[rr]);
        }
        __syncthreads();
        {
            u64 v = *(u64*)&ht[bl][dq * 4];
            cst64(&hout16[fhwr], v);
        }
        fbar(flags, fbase, GRU_NB, ++ep);
    }
}

// ---------------- sync-free per-batch match: split-chain ILP + prefetch ----------------
// Ws: [64][512][8]  bf16; Wg: [6][64][512][8] fam: 0 R_a, 1 Z_a, 2 N_a, 3 R_r, 4 Z_r, 5 N_r
__global__ __launch_bounds__(512, 1)
void match_pb(const unsigned short* __restrict__ Ws,
              const unsigned short* __restrict__ Wg,
              const unsigned short* __restrict__ OHWh_bt,
              const unsigned short* __restrict__ OHGI_bt,
              const float* __restrict__ m_bhh, const float* __restrict__ Walpha,
              const unsigned short* __restrict__ Yw_bb,
              const unsigned short* __restrict__ Y_bb,
              const int* __restrict__ prem, const int* __restrict__ hyp,
              float* __restrict__ r32)
{
    __shared__ unsigned ytp[64][512];   // 128 KB: Y tp-pair packed [tp/2][n]
    __shared__ float sarr[4 * SPAD];    // padded q-segments (bank-shifted)
    __shared__ float wal[4 * SPAD];
    __shared__ float part[512];
    __shared__ float lg[T_SZ];
    __shared__ unsigned lgp[64];
    __shared__ unsigned xa16[256];      // a packed bf16 pairs
    __shared__ unsigned xr16[256];      // r packed bf16 pairs
    __shared__ float xr32[512];         // r f32 (recurrence blend)

    const int b = blockIdx.x;
    const int tid = threadIdx.x;   // 0..511
    const int tp = tid >> 2, q = tid & 3;

    // Y -> tp-pair packed LDS (once)
    for (int s = 0; s < 8; ++s) {
        int idx = s * 512 + tid;            // 4096 jobs: rp 0..63, ng 0..63
        int rp = idx >> 6, n0 = (idx & 63) * 8;
        s16x8 y0 = *(const s16x8*)&Y_bb[((long)b * T_SZ + 2 * rp) * ND + n0];
        s16x8 y1 = *(const s16x8*)&Y_bb[((long)b * T_SZ + 2 * rp + 1) * ND + n0];
#pragma unroll
        for (int j = 0; j < 8; ++j)
            ytp[rp][n0 + j] = (unsigned)(unsigned short)y0[j]
                            | ((unsigned)(unsigned short)y1[j] << 16);
    }
    // Yw slice -> registers (once)
    s16x8 ywr[16];
#pragma unroll
    for (int i8 = 0; i8 < 16; ++i8)
        ywr[i8] = *(const s16x8*)&Yw_bb[((long)b * T_SZ + tp) * ND + q * 128 + i8 * 8];

    wal[(tid >> 7) * SPAD + (tid & 127)] = Walpha[tid];
    xr32[tid] = 0.0f;
    if (tid < 256) xr16[tid] = 0u;
    float mm = 0.f;
    if (tid < T_SZ) mm = (prem[b * T_SZ + tid] != 0) ? 0.f : 1000.f;
    __syncthreads();

    const float* sp  = &sarr[q * SPAD];
    const float* wap = &wal[q * SPAD];
    const int sw = (tid >> 7) * SPAD + (tid & 127);    // padded write slot for n = tid
    const u32x4* wsp4 = (const u32x4*)((const unsigned*)Ws + tid * 4);   // stride 512 per k8
    const u32x4* wgp4 = (const u32x4*)((const unsigned*)Wg + tid * 4);
    const u32x4* xa4 = (const u32x4*)xa16;
    const u32x4* xr4 = (const u32x4*)xr16;
    const unsigned ONE2 = 0x3F803F80u;

    for (int t = 0; t < T_SZ; ++t) {
        // ---- loop-top prefetch of t-dependent operands (phase-independent) ----
        const float ohw = b2f(OHWh_bt[((long)b * T_SZ + t) * ND + tid]);
        const unsigned short* og = OHGI_bt + ((long)b * T_SZ + t) * G3;
        const float ogR = b2f(og[tid]);
        const float ogZ = b2f(og[ND + tid]);
        const float ogN = b2f(og[2 * ND + tid]);
        const bool mk = hyp[b * T_SZ + t] != 0;

        // ---- phase 1: s[n] = r . W_r[:,n] + OHWh (2 accumulator chains) ----
        {
            float a0 = 0.f, a1 = 0.f;
#pragma unroll 4
            for (int k8 = 0; k8 < 64; ++k8) {
                u32x4 w = wsp4[(long)k8 * 512];
                u32x4 x = xr4[k8];
                a0 = dot2bf(w[0], x[0], a0);
                a1 = dot2bf(w[1], x[1], a1);
                a0 = dot2bf(w[2], x[2], a0);
                a1 = dot2bf(w[3], x[3], a1);
            }
            sarr[sw] = a0 + a1 + ohw;
        }
        __syncthreads();
        // ---- phase 2: logits (Yw regs, padded conflict-free LDS) ----
        {
            float acc = 0.f;
#pragma unroll
            for (int i8 = 0; i8 < 16; ++i8) {
                s16x8 yw = ywr[i8];
                f32x4 s0 = *(const f32x4*)&sp[i8 * 8];
                f32x4 s1 = *(const f32x4*)&sp[i8 * 8 + 4];
                f32x4 w0 = *(const f32x4*)&wap[i8 * 8];
                f32x4 w1 = *(const f32x4*)&wap[i8 * 8 + 4];
#pragma unroll
                for (int j = 0; j < 4; ++j)
                    acc += ftanh(b2f((unsigned short)yw[j]) + s0[j]) * w0[j];
#pragma unroll
                for (int j = 0; j < 4; ++j)
                    acc += ftanh(b2f((unsigned short)yw[4 + j]) + s1[j]) * w1[j];
            }
            part[tid] = acc;
        }
        __syncthreads();
        if (tid < T_SZ)
            lg[tid] = __expf(part[tid * 4] + part[tid * 4 + 1]
                           + part[tid * 4 + 2] + part[tid * 4 + 3] - mm);
        __syncthreads();
        if (tid < 64) lgp[tid] = pk2(lg[2 * tid], lg[2 * tid + 1]);
        __syncthreads();
        // ---- phase 3: a[n] via dot2 over tp-pairs (2 chains each) ----
        {
            float av0 = 0.f, av1 = 0.f, su0 = 0.f, su1 = 0.f;
#pragma unroll 4
            for (int i = 0; i < 64; i += 2) {
                unsigned l0 = lgp[i], l1 = lgp[i + 1];
                av0 = dot2bf(l0, ytp[i][tid], av0);
                su0 = dot2bf(l0, ONE2, su0);
                av1 = dot2bf(l1, ytp[i + 1][tid], av1);
                su1 = dot2bf(l1, ONE2, su1);
            }
            part[tid] = (av0 + av1) / (su0 + su1);
        }
        __syncthreads();
        if (tid < 256) xa16[tid] = pk2(part[2 * tid], part[2 * tid + 1]);
        __syncthreads();
        // ---- phase 4: gates via dot2, 6 independent chains + combine ----
        {
            float aRa = 0.f, aRr = 0.f, aZa = 0.f, aZr = 0.f, aGN = 0.f, aHN = 0.f;
#pragma unroll 2
            for (int k8 = 0; k8 < 64; ++k8) {
                u32x4 xa = xa4[k8];
                u32x4 xr = xr4[k8];
                const long ko = (long)k8 * 512;
                u32x4 wRa = wgp4[ko];
                u32x4 wZa = wgp4[ko + (1L << 15)];
                u32x4 wNa = wgp4[ko + (2L << 15)];
                u32x4 wRr = wgp4[ko + (3L << 15)];
                u32x4 wZr = wgp4[ko + (4L << 15)];
                u32x4 wNr = wgp4[ko + (5L << 15)];
#pragma unroll
                for (int j = 0; j < 4; ++j) {
                    aRa = dot2bf(wRa[j], xa[j], aRa);
                    aZa = dot2bf(wZa[j], xa[j], aZa);
                    aGN = dot2bf(wNa[j], xa[j], aGN);
                    aRr = dot2bf(wRr[j], xr[j], aRr);
                    aZr = dot2bf(wZr[j], xr[j], aZr);
                    aHN = dot2bf(wNr[j], xr[j], aHN);
                }
            }
            float rg = fsigmoid(aRa + aRr + ogR + m_bhh[tid]);
            float zg = fsigmoid(aZa + aZr + ogZ + m_bhh[ND + tid]);
            float ng = ftanh(aGN + ogN + rg * (aHN + m_bhh[2 * ND + tid]));
            float rp = xr32[tid];
            float rn = (1.0f - zg) * ng + zg * rp;
            float v = mk ? rn : rp;
            __syncthreads();                 // all GEMV reads of old r done
            xr32[tid] = v;
            part[tid] = v;
        }
        __syncthreads();
        if (tid < 256) xr16[tid] = pk2(part[2 * tid], part[2 * tid + 1]);
        __syncthreads();
    }
    r32[(long)b * ND + tid] = xr32[tid];
}

// ---------------- prep / misc ----------------
__global__ void prep_idx(const int* __restrict__ prem, const int* __restrict__ hyp,
                         int* __restrict__ idx_p, int* __restrict__ idx_h)
{
    int i = blockIdx.x * blockDim.x + threadIdx.x;
    if (i < B_SZ * T_SZ) {
        int t = i / B_SZ, b = i % B_SZ;
        idx_p[i] = prem[b * T_SZ + t];
        idx_h[i] = hyp[b * T_SZ + t];
    }
}

__global__ void conv_w(const float* __restrict__ in, unsigned short* __restrict__ out,
                       int N, int K, int Kpad, int ldIn, int colOff)
{
    long i = (long)blockIdx.x * blockDim.x + threadIdx.x;
    if (i >= (long)N * Kpad) return;
    int n = (int)(i / Kpad), k = (int)(i % Kpad);
    float v = (k < K) ? in[(long)n * ldIn + k + colOff] : 0.0f;
    out[i] = f2b(v);
}

__global__ void conv_wT(const float* __restrict__ in, unsigned short* __restrict__ out,
                        int N, int K, int Kpad, int ldIn)
{
    long i = (long)blockIdx.x * blockDim.x + threadIdx.x;
    if (i >= (long)N * Kpad) return;
    int n = (int)(i / Kpad), k = (int)(i % Kpad);
    float v = (k < K) ? in[(long)k * ldIn + n] : 0.0f;
    out[i] = f2b(v);
}

// Ws[k8][n][j] = W_r[k8*8+j][n]
__global__ void pack_ws(const float* __restrict__ Wr, unsigned short* __restrict__ out)
{
    long i = (long)blockIdx.x * blockDim.x + threadIdx.x;
    if (i >= 64L * 512 * 8) return;
    int k8 = (int)(i >> 12), n = (int)((i >> 3) & 511), j = (int)(i & 7);
    out[i] = f2b(Wr[(long)(k8 * 8 + j) * ND + n]);
}

// Wg[fam][k8][n][j]: fam 0..2 a-side (m_Wih cols 0..511), fam 3..5 r-side (m_Whh)
__global__ void pack_wg(const float* __restrict__ mWih, const float* __restrict__ mWhh,
                        unsigned short* __restrict__ out)
{
    long i = (long)blockIdx.x * blockDim.x + threadIdx.x;
    if (i >= 6L * 64 * 512 * 8) return;
    int fam = (int)(i >> 18);
    long rem = i & 262143;
    int k8 = (int)(rem >> 12), n = (int)((rem >> 3) & 511), j = (int)(rem & 7);
    int k = k8 * 8 + j;
    float v;
    if (fam < 3) v = mWih[(long)(fam * ND + n) * 1024 + k];
    else         v = mWhh[(long)((fam - 3) * ND + n) * ND + k];
    out[i] = f2b(v);
}

__global__ void zero_kernel(float* __restrict__ p, int n)
{
    int i = blockIdx.x * blockDim.x + threadIdx.x;
    if (i < n) p[i] = 0.0f;
}

__global__ void final_logits(const float* __restrict__ r, const float* __restrict__ outW,
                             const float* __restrict__ outb, float* __restrict__ out)
{
    int b = blockIdx.x;
    int lane = threadIdx.x;
    float a0 = 0.0f, a1 = 0.0f, a2 = 0.0f;
    for (int k = lane; k < ND; k += 64) {
        float rv = r[(long)b * ND + k];
        a0 += rv * outW[0 * ND + k];
        a1 += rv * outW[1 * ND + k];
        a2 += rv * outW[2 * ND + k];
    }
#pragma unroll
    for (int off = 32; off; off >>= 1) {
        a0 += __shfl_down(a0, off);
        a1 += __shfl_down(a1, off);
        a2 += __shfl_down(a2, off);
    }
    if (lane == 0) {
        float l0 = a0 + outb[0], l1 = a1 + outb[1], l2 = a2 + outb[2];
        float mx = fmaxf(l0, fmaxf(l1, l2));
        float se = expf(l0 - mx) + expf(l1 - mx) + expf(l2 - mx);
        float ls = mx + logf(se);
        out[b * 3 + 0] = l0 - ls;
        out[b * 3 + 1] = l1 - ls;
        out[b * 3 + 2] = l2 - ls;
    }
}

// ---------------- host ----------------
extern "C" void kernel_launch(void* const* d_in, const int* in_sizes, int n_in,
                              void* d_out, int out_size, void* d_ws, size_t ws_size,
                              hipStream_t stream)
{
    const int*   prem    = (const int*)d_in[0];
    const int*   hyp     = (const int*)d_in[1];
    const float* E       = (const float*)d_in[2];
    const float* p_Wih   = (const float*)d_in[3];
    const float* p_Whh   = (const float*)d_in[4];
    const float* p_bih   = (const float*)d_in[5];
    const float* p_bhh   = (const float*)d_in[6];
    const float* h_Wih   = (const float*)d_in[7];
    const float* h_Whh   = (const float*)d_in[8];
    const float* h_bih   = (const float*)d_in[9];
    const float* h_bhh   = (const float*)d_in[10];
    const float* m_Wih   = (const float*)d_in[11];
    const float* m_Whh   = (const float*)d_in[12];
    const float* m_bih   = (const float*)d_in[13];
    const float* m_bhh   = (const float*)d_in[14];
    const float* W_y     = (const float*)d_in[15];
    const float* W_h     = (const float*)d_in[16];
    const float* W_r     = (const float*)d_in[17];
    const float* W_alpha = (const float*)d_in[18];
    const float* out_W   = (const float*)d_in[19];
    const float* out_b   = (const float*)d_in[20];
    float* out = (float*)d_out;

    const int MB = T_SZ * B_SZ;  // 16384
    const int NFLAGS = NREP * NFID * FPAD;

    float* ws = (float*)d_ws;
    size_t off = 0;
    float* GI    = ws + off; off += (size_t)MB * G3;
    float* h32   = ws + off; off += (size_t)B_SZ * ND;
    float* r32   = ws + off; off += (size_t)B_SZ * ND;
    unsigned* flags = (unsigned*)(ws + off); off += NFLAGS;
    int* idx_p = (int*)(ws + off); off += (size_t)B_SZ * T_SZ;
    int* idx_h = (int*)(ws + off); off += (size_t)B_SZ * T_SZ;
    unsigned short* ub = (unsigned short*)(ws + off);
    size_t uoff = 0;
    unsigned short* o_p_bt = ub + uoff; uoff += (size_t)MB * ND;   // Y
    unsigned short* o_h_bt = ub + uoff; uoff += (size_t)MB * ND;
    unsigned short* Yw_bb  = ub + uoff; uoff += (size_t)MB * ND;
    unsigned short* OHWh_bt= ub + uoff; uoff += (size_t)MB * ND;
    unsigned short* OHGI_bt= ub + uoff; uoff += (size_t)MB * G3;
    unsigned short* h16a   = ub + uoff; uoff += (size_t)B_SZ * ND;
    unsigned short* h16b   = ub + uoff; uoff += (size_t)B_SZ * ND;
    unsigned short* pWih_b = ub + uoff; uoff += (size_t)G3 * 320;
    unsigned short* hWih_b = ub + uoff; uoff += (size_t)G3 * 320;
    unsigned short* pWhh_b = ub + uoff; uoff += (size_t)G3 * ND;
    unsigned short* hWhh_b = ub + uoff; uoff += (size_t)G3 * ND;
    unsigned short* mWihR  = ub + uoff; uoff += (size_t)G3 * ND;
    unsigned short* WyT_b  = ub + uoff; uoff += (size_t)ND * ND;
    unsigned short* WhT_b  = ub + uoff; uoff += (size_t)ND * ND;
    unsigned short* Ws_p   = ub + uoff; uoff += 64L * 512 * 8;
    unsigned short* Wg_p   = ub + uoff; uoff += 6L * 64 * 512 * 8;
    off += (uoff + 1) / 2;
    if (ws_size < off * sizeof(float)) return;

    auto cblk = [](long n) { return (int)((n + 255) / 256); };

    // ---- prep ----
    prep_idx<<<cblk(MB), 256, 0, stream>>>(prem, hyp, idx_p, idx_h);
    conv_w <<<cblk((long)G3 * 320), 256, 0, stream>>>(p_Wih, pWih_b, G3, EMBD, 320, EMBD, 0);
    conv_w <<<cblk((long)G3 * 320), 256, 0, stream>>>(h_Wih, hWih_b, G3, EMBD, 320, EMBD, 0);
    conv_w <<<cblk((long)G3 * ND), 256, 0, stream>>>(p_Whh, pWhh_b, G3, ND, ND, ND, 0);
    conv_w <<<cblk((long)G3 * ND), 256, 0, stream>>>(h_Whh, hWhh_b, G3, ND, ND, ND, 0);
    conv_w <<<cblk((long)G3 * ND), 256, 0, stream>>>(m_Wih, mWihR, G3, ND, ND, 2 * ND, ND);
    conv_wT<<<cblk((long)ND * ND), 256, 0, stream>>>(W_y, WyT_b, ND, ND, ND, ND);
    conv_wT<<<cblk((long)ND * ND), 256, 0, stream>>>(W_h, WhT_b, ND, ND, ND, ND);
    pack_ws<<<cblk(64L * 512 * 8), 256, 0, stream>>>(W_r, Ws_p);
    pack_wg<<<cblk(6L * 64 * 512 * 8), 256, 0, stream>>>(m_Wih, m_Whh, Wg_p);
    zero_kernel<<<cblk(B_SZ * ND), 256, 0, stream>>>(h32, B_SZ * ND);
    zero_kernel<<<cblk(B_SZ * ND / 2), 256, 0, stream>>>((float*)h16a, B_SZ * ND / 2);
    zero_kernel<<<cblk(NFLAGS), 256, 0, stream>>>((float*)flags, NFLAGS);

    // ---- premise ----
    {
        dim3 g(G3 / 64, MB / 64);
        mfma_gemm<float, false><<<g, 256, 0, stream>>>(E, idx_p, pWih_b, p_bih, GI,
                                                       MB, G3, EMBD, EMBD, 320, G3);
    }
    gru_chain<<<GRU_NB, 256, 0, stream>>>(pWhh_b, GI, p_bhh, prem, h32, h16a, h16b,
                                          o_p_bt, flags, FB_GRUP);

    // ---- hypothesis ----
    {
        dim3 g(G3 / 64, MB / 64);
        mfma_gemm<float, false><<<g, 256, 0, stream>>>(E, idx_h, hWih_b, h_bih, GI,
                                                       MB, G3, EMBD, EMBD, 320, G3);
    }
    gru_chain<<<GRU_NB, 256, 0, stream>>>(hWhh_b, GI, h_bhh, hyp, h32, h16a, h16b,
                                          o_h_bt, flags, FB_GRUH);

    // ---- attention precompute (all [b][t]-row layouts) ----
    {
        dim3 g(ND / 64, MB / 64);
        mfma_gemm<unsigned short, true><<<g, 256, 0, stream>>>(o_p_bt, nullptr, WyT_b, nullptr,
                                                               Yw_bb, MB, ND, ND, ND, ND, ND);
        mfma_gemm<unsigned short, true><<<g, 256, 0, stream>>>(o_h_bt, nullptr, WhT_b, nullptr,
                                                               OHWh_bt, MB, ND, ND, ND, ND, ND);
        dim3 g2(G3 / 64, MB / 64);
        mfma_gemm<unsigned short, true><<<g2, 256, 0, stream>>>(o_h_bt, nullptr, mWihR, m_bih,
                                                                OHGI_bt, MB, G3, ND, ND, ND, G3);
    }

    // ---- match: sync-free, one block per batch element ----
    match_pb<<<B_SZ, 512, 0, stream>>>(Ws_p, Wg_p, OHWh_bt, OHGI_bt, m_bhh, W_alpha,
                                       Yw_bb, o_p_bt, prem, hyp, r32);

    final_logits<<<B_SZ, 64, 0, stream>>>(r32, out_W, out_b, out);
}

// Round 21
// 6498.188 us; speedup vs baseline: 1.6723x; 1.0099x over previous
//
#include <hip/hip_runtime.h>
#include <math.h>

#define B_SZ 128
#define T_SZ 128
#define EMBD 300
#define ND 512
#define G3 1536
#define FPAD 32    // flag padding stride (u32s) = 128 B
#define NFID 128   // flag ids per replica
#define NREP 8     // flag replicas
#define SPAD 132   // padded q-segment stride (floats): bank shift 4 per q

typedef short s16x8 __attribute__((ext_vector_type(8)));
typedef float f32x4 __attribute__((ext_vector_type(4)));
typedef unsigned u32x4 __attribute__((ext_vector_type(4)));
typedef unsigned long long u64;

__device__ __forceinline__ unsigned short f2b(float x) {
    unsigned u = __float_as_uint(x);
    unsigned r = (u + 0x7fff + ((u >> 16) & 1)) >> 16;  // RNE
    return (unsigned short)r;
}
__device__ __forceinline__ float b2f(unsigned short v) {
    return __uint_as_float(((unsigned)v) << 16);
}
__device__ __forceinline__ unsigned pk2(float lo, float hi) {
    return (unsigned)f2b(lo) | ((unsigned)f2b(hi) << 16);
}
__device__ __forceinline__ float fsigmoid(float x) { return 1.0f / (1.0f + __expf(-x)); }
__device__ __forceinline__ float ftanh(float x) { return 1.0f - 2.0f / (__expf(2.0f * x) + 1.0f); }

// packed bf16 dot2: c += a.lo*b.lo + a.hi*b.hi (single VOP3P instruction)
__device__ __forceinline__ float dot2bf(unsigned a, unsigned b, float c) {
    asm("v_dot2_f32_bf16 %0, %1, %2, %0" : "+v"(c) : "v"(a), "v"(b));
    return c;
}

__device__ __forceinline__ f32x4 mfma16(s16x8 a, s16x8 b, f32x4 c) {
    return __builtin_amdgcn_mfma_f32_16x16x32_bf16(a, b, c, 0, 0, 0);
}

// ---- coherent (LLC-point, fence-free) helpers (GRU chains only) ----
__device__ __forceinline__ u64 cld64(const void* p) {
    return __hip_atomic_load((const u64*)p, __ATOMIC_RELAXED, __HIP_MEMORY_SCOPE_AGENT);
}
__device__ __forceinline__ void cst64(void* p, u64 v) {
    __hip_atomic_store((u64*)p, v, __ATOMIC_RELAXED, __HIP_MEMORY_SCOPE_AGENT);
}
__device__ __forceinline__ unsigned cld32(const void* p) {
    return __hip_atomic_load((const unsigned*)p, __ATOMIC_RELAXED, __HIP_MEMORY_SCOPE_AGENT);
}
__device__ __forceinline__ void cst32(void* p, unsigned v) {
    __hip_atomic_store((unsigned*)p, v, __ATOMIC_RELAXED, __HIP_MEMORY_SCOPE_AGENT);
}
__device__ __forceinline__ s16x8 cld_frag(const unsigned short* p) {
    union { u64 q[2]; s16x8 v; } u;
    u.q[0] = cld64(p);
    u.q[1] = cld64(p + 4);
    return u.v;
}

// ---- replicated-flag grid barrier (GRU chains) ----
__device__ __forceinline__ void postflag(unsigned* flags, int base, int id, unsigned ep)
{
    if (threadIdx.x < NREP)
        cst32(&flags[((long)threadIdx.x * NFID + base + id) * FPAD], ep);
}
__device__ __forceinline__ void waitflags(const unsigned* flags, int base, int n,
                                          unsigned ep, int rep)
{
    const unsigned* fr = flags + (long)rep * NFID * FPAD;
    if (threadIdx.x < 64) {
#pragma unroll 1
        for (int i = threadIdx.x; i < n; i += 64)
            while (cld32(&fr[(long)(base + i) * FPAD]) < ep)
                __builtin_amdgcn_s_sleep(2);
    }
    __syncthreads();
}
__device__ __forceinline__ void fbar(unsigned* flags, int base, int nb, unsigned ep)
{
    __syncthreads();
    postflag(flags, base, blockIdx.x & 63, ep);
    waitflags(flags, base, nb, ep, blockIdx.x & 7);
}

#define FB_GRUP 0
#define FB_GRUH 64

// ---------------- generic MFMA GEMM (precompute only) ----------------
template<typename AT, bool OB>
__global__ __launch_bounds__(256)
void mfma_gemm(const AT* __restrict__ A, const int* __restrict__ idxA,
               const unsigned short* __restrict__ Wb, const float* __restrict__ bias,
               void* __restrict__ Cv,
               int M, int N, int K, int ldA, int Kpad, int ldC)
{
    __shared__ unsigned short As[64][40];
    __shared__ unsigned short Bs[64][40];
    const int tid = threadIdx.x;
    const int wv = tid >> 6, lane = tid & 63;
    const int wm = wv >> 1, wn = wv & 1;
    const int m0 = blockIdx.y * 64, n0 = blockIdx.x * 64;

    f32x4 acc[2][2] = {{{0.f,0.f,0.f,0.f},{0.f,0.f,0.f,0.f}},
                       {{0.f,0.f,0.f,0.f},{0.f,0.f,0.f,0.f}}};
    const int r_st = tid >> 2, k_st = (tid & 3) * 8;

    long arow = -1;
    {
        int gm = m0 + r_st;
        if (gm < M) arow = idxA ? (long)idxA[gm] : (long)gm;
    }

    const int kIters = (K + 31) / 32;
    for (int it = 0; it < kIters; ++it) {
        const int kg = it * 32 + k_st;
        {
            s16x8 pk = {0,0,0,0,0,0,0,0};
            if (arow >= 0) {
                if constexpr (sizeof(AT) == 2) {
                    if (kg + 8 <= K) {
                        pk = *(const s16x8*)((const unsigned short*)A + arow * (long)ldA + kg);
                    } else {
#pragma unroll
                        for (int j = 0; j < 8; ++j)
                            if (kg + j < K) pk[j] = (short)((const unsigned short*)A)[arow * (long)ldA + kg + j];
                    }
                } else {
                    if (kg + 8 <= K) {
                        const float* p = (const float*)A + arow * (long)ldA + kg;
                        f32x4 u0 = *(const f32x4*)p;
                        f32x4 u1 = *(const f32x4*)(p + 4);
#pragma unroll
                        for (int j = 0; j < 4; ++j) { pk[j] = (short)f2b(u0[j]); pk[4+j] = (short)f2b(u1[j]); }
                    } else {
#pragma unroll
                        for (int j = 0; j < 8; ++j) {
                            int kk = kg + j;
                            if (kk < K) pk[j] = (short)f2b(((const float*)A)[arow * (long)ldA + kk]);
                        }
                    }
                }
            }
            *(s16x8*)&As[r_st][k_st] = pk;
        }
        {
            int gn = n0 + r_st;
            s16x8 pk = {0,0,0,0,0,0,0,0};
            if (gn < N) pk = *(const s16x8*)&Wb[(long)gn * Kpad + kg];
            *(s16x8*)&Bs[r_st][k_st] = pk;
        }
        __syncthreads();
        {
            const int koff = (lane >> 4) * 8;
            s16x8 af[2], bfr[2];
#pragma unroll
            for (int f = 0; f < 2; ++f) {
                af[f]  = *(s16x8*)&As[wm * 32 + f * 16 + (lane & 15)][koff];
                bfr[f] = *(s16x8*)&Bs[wn * 32 + f * 16 + (lane & 15)][koff];
            }
#pragma unroll
            for (int fi = 0; fi < 2; ++fi)
#pragma unroll
                for (int fj = 0; fj < 2; ++fj)
                    acc[fi][fj] = mfma16(af[fi], bfr[fj], acc[fi][fj]);
        }
        __syncthreads();
    }
#pragma unroll
    for (int fi = 0; fi < 2; ++fi)
#pragma unroll
        for (int fj = 0; fj < 2; ++fj)
#pragma unroll
            for (int r = 0; r < 4; ++r) {
                int m = m0 + wm * 32 + fi * 16 + (lane >> 4) * 4 + r;
                int n = n0 + wn * 32 + fj * 16 + (lane & 15);
                if (m < M && n < N) {
                    float v = acc[fi][fj][r];
                    if (bias) v += bias[n];
                    if constexpr (OB) ((unsigned short*)Cv)[(long)m * ldC + n] = f2b(v);
                    else               ((float*)Cv)[(long)m * ldC + n] = v;
                }
            }
}

// ---------------- persistent GRU chain (unchanged) ----------------
#define GRU_NB 64
__global__ __launch_bounds__(256, 1)
void gru_chain(const unsigned short* __restrict__ Whh_b, const float* __restrict__ GI,
               const float* __restrict__ bhh, const int* __restrict__ toks,
               float* __restrict__ h32,
               unsigned short* __restrict__ h16a, unsigned short* __restrict__ h16b,
               unsigned short* __restrict__ o_bt,
               unsigned* __restrict__ flags, int fbase)
{
    __shared__ unsigned short wlds[3][16][512];   // 48 KB
    __shared__ unsigned short ht[64][20];
    const int tid = threadIdx.x;
    const int wv = tid >> 6, lane = tid & 63;
    const int dt = blockIdx.x & 31, bh = blockIdx.x >> 5;
    const int b0 = bh * 64;

    for (int s = 0; s < 12; ++s) {
        int slot = tid + s * 256;
        int g = slot >> 10, rem = slot & 1023, ks = rem >> 6, ln = rem & 63;
        int row = g * ND + dt * 16 + (ln & 15);
        int k = ks * 32 + (ln >> 4) * 8;
        *(s16x8*)&wlds[g][ks][ln * 8] = *(const s16x8*)&Whh_b[(long)row * ND + k];
    }
    __syncthreads();

    const int d = dt * 16 + (lane & 15);
    const int brow = b0 + wv * 16 + (lane >> 4) * 4;
    const long fhrd = ((long)(bh * 4 + wv) * 16) << 9;

    const int bl = tid & 63, dq = tid >> 6;
    const long fhwr = (((long)(bh * 4 + (bl >> 4)) * 16 + (dt >> 1)) << 9)
                    + (((((dt & 1) * 16 + dq * 4) >> 3) * 16 + (bl & 15)) * 8)
                    + (((dt & 1) * 16 + dq * 4) & 7);

    float hreg[4];
#pragma unroll
    for (int rr = 0; rr < 4; ++rr) hreg[rr] = h32[(long)(brow + rr) * ND + d];

    float o_run[4] = {0.f, 0.f, 0.f, 0.f};
    unsigned ep = 0;

    for (int t = 0; t < T_SZ; ++t) {
        const unsigned short* hin16 = (t & 1) ? h16b : h16a;
        unsigned short* hout16 = (t & 1) ? h16a : h16b;

        const float* git = GI + (long)t * (B_SZ * G3);
        float gi_r[4], gi_z[4], gi_n[4]; int mk[4];
#pragma unroll
        for (int rr = 0; rr < 4; ++rr) {
            int b = brow + rr;
            gi_r[rr] = git[(long)b * G3 + d];
            gi_z[rr] = git[(long)b * G3 + ND + d];
            gi_n[rr] = git[(long)b * G3 + 2 * ND + d];
            mk[rr]   = toks[b * T_SZ + t];
        }

        f32x4 acc0 = {0,0,0,0}, acc1 = {0,0,0,0}, acc2 = {0,0,0,0};
#pragma unroll
        for (int ks = 0; ks < 16; ++ks) {
            s16x8 a  = cld_frag(&hin16[fhrd + ((long)ks << 9) + lane * 8]);
            s16x8 br = *(s16x8*)&wlds[0][ks][lane * 8];
            s16x8 bz = *(s16x8*)&wlds[1][ks][lane * 8];
            s16x8 bn = *(s16x8*)&wlds[2][ks][lane * 8];
            acc0 = mfma16(a, br, acc0);
            acc1 = mfma16(a, bz, acc1);
            acc2 = mfma16(a, bn, acc2);
        }

#pragma unroll
        for (int rr = 0; rr < 4; ++rr) {
            int b = brow + rr;
            float rg = fsigmoid(gi_r[rr] + acc0[rr] + bhh[d]);
            float zg = fsigmoid(gi_z[rr] + acc1[rr] + bhh[ND + d]);
            float ng = ftanh(gi_n[rr] + rg * (acc2[rr] + bhh[2 * ND + d]));
            float hr = (1.0f - zg) * ng + zg * hreg[rr];
            bool m = mk[rr] != 0;
            float hn = m ? hr : hreg[rr];
            hreg[rr] = hn;
            ht[b - b0][lane & 15] = f2b(hn);
            if (t == T_SZ - 1) h32[(long)b * ND + d] = hn;
            o_run[rr] = (t == 0) ? hr : (m ? hr : o_run[rr]);
            o_bt[((long)b * T_SZ + t) * ND + d] = f2b(o_run[rr]);
        }
        __syncthreads();
        {
            u64 v = *(u64*)&ht[bl][dq * 4];
            cst64(&hout16[fhwr], v);
        }
        fbar(flags, fbase, GRU_NB, ++ep);
    }
}

// ---------------- sync-free per-batch match: 6 barriers/step ----------------
// Ws: [64][512][8]  bf16; Wg: [6][64][512][8] fam: 0 R_a, 1 Z_a, 2 N_a, 3 R_r, 4 Z_r, 5 N_r
__global__ __launch_bounds__(512, 1)
void match_pb(const unsigned short* __restrict__ Ws,
              const unsigned short* __restrict__ Wg,
              const unsigned short* __restrict__ OHWh_bt,
              const unsigned short* __restrict__ OHGI_bt,
              const float* __restrict__ m_bhh, const float* __restrict__ Walpha,
              const unsigned short* __restrict__ Yw_bb,
              const unsigned short* __restrict__ Y_bb,
              const int* __restrict__ prem, const int* __restrict__ hyp,
              float* __restrict__ r32)
{
    __shared__ unsigned ytp[64][512];   // 128 KB: Y tp-pair packed [tp/2][n]
    __shared__ float sarr[4 * SPAD];    // padded q-segments (bank-shifted)
    __shared__ float wal[4 * SPAD];
    __shared__ float part[512];
    __shared__ unsigned lgp[64];
    __shared__ unsigned xa16[256];      // a packed bf16 pairs
    __shared__ unsigned xr16[256];      // r packed bf16 pairs
    __shared__ float xr32[512];         // r f32 (recurrence blend)

    const int b = blockIdx.x;
    const int tid = threadIdx.x;   // 0..511
    const int tp = tid >> 2, q = tid & 3;

    // Y -> tp-pair packed LDS (once)
    for (int s = 0; s < 8; ++s) {
        int idx = s * 512 + tid;            // 4096 jobs: rp 0..63, ng 0..63
        int rp = idx >> 6, n0 = (idx & 63) * 8;
        s16x8 y0 = *(const s16x8*)&Y_bb[((long)b * T_SZ + 2 * rp) * ND + n0];
        s16x8 y1 = *(const s16x8*)&Y_bb[((long)b * T_SZ + 2 * rp + 1) * ND + n0];
#pragma unroll
        for (int j = 0; j < 8; ++j)
            ytp[rp][n0 + j] = (unsigned)(unsigned short)y0[j]
                            | ((unsigned)(unsigned short)y1[j] << 16);
    }
    // Yw slice -> registers (once)
    s16x8 ywr[16];
#pragma unroll
    for (int i8 = 0; i8 < 16; ++i8)
        ywr[i8] = *(const s16x8*)&Yw_bb[((long)b * T_SZ + tp) * ND + q * 128 + i8 * 8];

    wal[(tid >> 7) * SPAD + (tid & 127)] = Walpha[tid];
    xr32[tid] = 0.0f;
    if (tid < 256) xr16[tid] = 0u;
    float mm0 = 0.f, mm1 = 0.f;
    if (tid < 64) {
        mm0 = (prem[b * T_SZ + 2 * tid] != 0) ? 0.f : 1000.f;
        mm1 = (prem[b * T_SZ + 2 * tid + 1] != 0) ? 0.f : 1000.f;
    }
    __syncthreads();

    const float* sp  = &sarr[q * SPAD];
    const float* wap = &wal[q * SPAD];
    const int sw = (tid >> 7) * SPAD + (tid & 127);    // padded write slot for n = tid
    const u32x4* wsp4 = (const u32x4*)((const unsigned*)Ws + tid * 4);   // stride 512 per k8
    const u32x4* wgp4 = (const u32x4*)((const unsigned*)Wg + tid * 4);
    const u32x4* xa4 = (const u32x4*)xa16;
    const u32x4* xr4 = (const u32x4*)xr16;
    const unsigned ONE2 = 0x3F803F80u;

    for (int t = 0; t < T_SZ; ++t) {
        // ---- loop-top prefetch of t-dependent operands (phase-independent) ----
        const float ohw = b2f(OHWh_bt[((long)b * T_SZ + t) * ND + tid]);
        const unsigned short* og = OHGI_bt + ((long)b * T_SZ + t) * G3;
        const float ogR = b2f(og[tid]);
        const float ogZ = b2f(og[ND + tid]);
        const float ogN = b2f(og[2 * ND + tid]);
        const bool mk = hyp[b * T_SZ + t] != 0;

        // ---- phase 1: s[n] = r . W_r[:,n] + OHWh (2 accumulator chains) ----
        {
            float a0 = 0.f, a1 = 0.f;
#pragma unroll 4
            for (int k8 = 0; k8 < 64; ++k8) {
                u32x4 w = wsp4[(long)k8 * 512];
                u32x4 x = xr4[k8];
                a0 = dot2bf(w[0], x[0], a0);
                a1 = dot2bf(w[1], x[1], a1);
                a0 = dot2bf(w[2], x[2], a0);
                a1 = dot2bf(w[3], x[3], a1);
            }
            sarr[sw] = a0 + a1 + ohw;
        }
        __syncthreads();   // B1: sarr ready
        // ---- phase 2: logits (Yw regs, padded conflict-free LDS) ----
        {
            float acc = 0.f;
#pragma unroll
            for (int i8 = 0; i8 < 16; ++i8) {
                s16x8 yw = ywr[i8];
                f32x4 s0 = *(const f32x4*)&sp[i8 * 8];
                f32x4 s1 = *(const f32x4*)&sp[i8 * 8 + 4];
                f32x4 w0 = *(const f32x4*)&wap[i8 * 8];
                f32x4 w1 = *(const f32x4*)&wap[i8 * 8 + 4];
#pragma unroll
                for (int j = 0; j < 4; ++j)
                    acc += ftanh(b2f((unsigned short)yw[j]) + s0[j]) * w0[j];
#pragma unroll
                for (int j = 0; j < 4; ++j)
                    acc += ftanh(b2f((unsigned short)yw[4 + j]) + s1[j]) * w1[j];
            }
            part[tid] = acc;
        }
        __syncthreads();   // B2: part ready
        // ---- fused: logit reduce + exp + pack (tid<64) ----
        if (tid < 64) {
            float l0 = part[8 * tid]     + part[8 * tid + 1]
                     + part[8 * tid + 2] + part[8 * tid + 3];
            float l1 = part[8 * tid + 4] + part[8 * tid + 5]
                     + part[8 * tid + 6] + part[8 * tid + 7];
            lgp[tid] = pk2(__expf(l0 - mm0), __expf(l1 - mm1));
        }
        __syncthreads();   // B3: lgp ready
        // ---- phase 3: a[n] via dot2 over tp-pairs + shfl-pack ----
        {
            float av0 = 0.f, av1 = 0.f, su0 = 0.f, su1 = 0.f;
#pragma unroll 4
            for (int i = 0; i < 64; i += 2) {
                unsigned l0 = lgp[i], l1 = lgp[i + 1];
                av0 = dot2bf(l0, ytp[i][tid], av0);
                su0 = dot2bf(l0, ONE2, su0);
                av1 = dot2bf(l1, ytp[i + 1][tid], av1);
                su1 = dot2bf(l1, ONE2, su1);
            }
            float val = (av0 + av1) / (su0 + su1);
            float oth = __shfl_down(val, 1);
            if (!(tid & 1)) xa16[tid >> 1] = pk2(val, oth);
        }
        __syncthreads();   // B4: xa16 ready
        // ---- phase 4: gates via dot2, 6 independent chains + combine ----
        {
            float aRa = 0.f, aRr = 0.f, aZa = 0.f, aZr = 0.f, aGN = 0.f, aHN = 0.f;
#pragma unroll 2
            for (int k8 = 0; k8 < 64; ++k8) {
                u32x4 xa = xa4[k8];
                u32x4 xr = xr4[k8];
                const long ko = (long)k8 * 512;
                u32x4 wRa = wgp4[ko];
                u32x4 wZa = wgp4[ko + (1L << 15)];
                u32x4 wNa = wgp4[ko + (2L << 15)];
                u32x4 wRr = wgp4[ko + (3L << 15)];
                u32x4 wZr = wgp4[ko + (4L << 15)];
                u32x4 wNr = wgp4[ko + (5L << 15)];
#pragma unroll
                for (int j = 0; j < 4; ++j) {
                    aRa = dot2bf(wRa[j], xa[j], aRa);
                    aZa = dot2bf(wZa[j], xa[j], aZa);
                    aGN = dot2bf(wNa[j], xa[j], aGN);
                    aRr = dot2bf(wRr[j], xr[j], aRr);
                    aZr = dot2bf(wZr[j], xr[j], aZr);
                    aHN = dot2bf(wNr[j], xr[j], aHN);
                }
            }
            float rg = fsigmoid(aRa + aRr + ogR + m_bhh[tid]);
            float zg = fsigmoid(aZa + aZr + ogZ + m_bhh[ND + tid]);
            float ng = ftanh(aGN + ogN + rg * (aHN + m_bhh[2 * ND + tid]));
            float rp = xr32[tid];
            float rn = (1.0f - zg) * ng + zg * rp;
            float v = mk ? rn : rp;
            __syncthreads();   // B5: all GEMV reads of old xr16 done
            xr32[tid] = v;
            float ov = __shfl_down(v, 1);
            if (!(tid & 1)) xr16[tid >> 1] = pk2(v, ov);
        }
        __syncthreads();   // B6: xr16 ready for next step
    }
    r32[(long)b * ND + tid] = xr32[tid];
}

// ---------------- prep / misc ----------------
__global__ void prep_idx(const int* __restrict__ prem, const int* __restrict__ hyp,
                         int* __restrict__ idx_p, int* __restrict__ idx_h)
{
    int i = blockIdx.x * blockDim.x + threadIdx.x;
    if (i < B_SZ * T_SZ) {
        int t = i / B_SZ, b = i % B_SZ;
        idx_p[i] = prem[b * T_SZ + t];
        idx_h[i] = hyp[b * T_SZ + t];
    }
}

__global__ void conv_w(const float* __restrict__ in, unsigned short* __restrict__ out,
                       int N, int K, int Kpad, int ldIn, int colOff)
{
    long i = (long)blockIdx.x * blockDim.x + threadIdx.x;
    if (i >= (long)N * Kpad) return;
    int n = (int)(i / Kpad), k = (int)(i % Kpad);
    float v = (k < K) ? in[(long)n * ldIn + k + colOff] : 0.0f;
    out[i] = f2b(v);
}

__global__ void conv_wT(const float* __restrict__ in, unsigned short* __restrict__ out,
                        int N, int K, int Kpad, int ldIn)
{
    long i = (long)blockIdx.x * blockDim.x + threadIdx.x;
    if (i >= (long)N * Kpad) return;
    int n = (int)(i / Kpad), k = (int)(i % Kpad);
    float v = (k < K) ? in[(long)k * ldIn + n] : 0.0f;
    out[i] = f2b(v);
}

// Ws[k8][n][j] = W_r[k8*8+j][n]
__global__ void pack_ws(const float* __restrict__ Wr, unsigned short* __restrict__ out)
{
    long i = (long)blockIdx.x * blockDim.x + threadIdx.x;
    if (i >= 64L * 512 * 8) return;
    int k8 = (int)(i >> 12), n = (int)((i >> 3) & 511), j = (int)(i & 7);
    out[i] = f2b(Wr[(long)(k8 * 8 + j) * ND + n]);
}

// Wg[fam][k8][n][j]: fam 0..2 a-side (m_Wih cols 0..511), fam 3..5 r-side (m_Whh)
__global__ void pack_wg(const float* __restrict__ mWih, const float* __restrict__ mWhh,
                        unsigned short* __restrict__ out)
{
    long i = (long)blockIdx.x * blockDim.x + threadIdx.x;
    if (i >= 6L * 64 * 512 * 8) return;
    int fam = (int)(i >> 18);
    long rem = i & 262143;
    int k8 = (int)(rem >> 12), n = (int)((rem >> 3) & 511), j = (int)(rem & 7);
    int k = k8 * 8 + j;
    float v;
    if (fam < 3) v = mWih[(long)(fam * ND + n) * 1024 + k];
    else         v = mWhh[(long)((fam - 3) * ND + n) * ND + k];
    out[i] = f2b(v);
}

__global__ void zero_kernel(float* __restrict__ p, int n)
{
    int i = blockIdx.x * blockDim.x + threadIdx.x;
    if (i < n) p[i] = 0.0f;
}

__global__ void final_logits(const float* __restrict__ r, const float* __restrict__ outW,
                             const float* __restrict__ outb, float* __restrict__ out)
{
    int b = blockIdx.x;
    int lane = threadIdx.x;
    float a0 = 0.0f, a1 = 0.0f, a2 = 0.0f;
    for (int k = lane; k < ND; k += 64) {
        float rv = r[(long)b * ND + k];
        a0 += rv * outW[0 * ND + k];
        a1 += rv * outW[1 * ND + k];
        a2 += rv * outW[2 * ND + k];
    }
#pragma unroll
    for (int off = 32; off; off >>= 1) {
        a0 += __shfl_down(a0, off);
        a1 += __shfl_down(a1, off);
        a2 += __shfl_down(a2, off);
    }
    if (lane == 0) {
        float l0 = a0 + outb[0], l1 = a1 + outb[1], l2 = a2 + outb[2];
        float mx = fmaxf(l0, fmaxf(l1, l2));
        float se = expf(l0 - mx) + expf(l1 - mx) + expf(l2 - mx);
        float ls = mx + logf(se);
        out[b * 3 + 0] = l0 - ls;
        out[b * 3 + 1] = l1 - ls;
        out[b * 3 + 2] = l2 - ls;
    }
}

// ---------------- host ----------------
extern "C" void kernel_launch(void* const* d_in, const int* in_sizes, int n_in,
                              void* d_out, int out_size, void* d_ws, size_t ws_size,
                              hipStream_t stream)
{
    const int*   prem    = (const int*)d_in[0];
    const int*   hyp     = (const int*)d_in[1];
    const float* E       = (const float*)d_in[2];
    const float* p_Wih   = (const float*)d_in[3];
    const float* p_Whh   = (const float*)d_in[4];
    const float* p_bih   = (const float*)d_in[5];
    const float* p_bhh   = (const float*)d_in[6];
    const float* h_Wih   = (const float*)d_in[7];
    const float* h_Whh   = (const float*)d_in[8];
    const float* h_bih   = (const float*)d_in[9];
    const float* h_bhh   = (const float*)d_in[10];
    const float* m_Wih   = (const float*)d_in[11];
    const float* m_Whh   = (const float*)d_in[12];
    const float* m_bih   = (const float*)d_in[13];
    const float* m_bhh   = (const float*)d_in[14];
    const float* W_y     = (const float*)d_in[15];
    const float* W_h     = (const float*)d_in[16];
    const float* W_r     = (const float*)d_in[17];
    const float* W_alpha = (const float*)d_in[18];
    const float* out_W   = (const float*)d_in[19];
    const float* out_b   = (const float*)d_in[20];
    float* out = (float*)d_out;

    const int MB = T_SZ * B_SZ;  // 16384
    const int NFLAGS = NREP * NFID * FPAD;

    float* ws = (float*)d_ws;
    size_t off = 0;
    float* GI    = ws + off; off += (size_t)MB * G3;
    float* h32   = ws + off; off += (size_t)B_SZ * ND;
    float* r32   = ws + off; off += (size_t)B_SZ * ND;
    unsigned* flags = (unsigned*)(ws + off); off += NFLAGS;
    int* idx_p = (int*)(ws + off); off += (size_t)B_SZ * T_SZ;
    int* idx_h = (int*)(ws + off); off += (size_t)B_SZ * T_SZ;
    unsigned short* ub = (unsigned short*)(ws + off);
    size_t uoff = 0;
    unsigned short* o_p_bt = ub + uoff; uoff += (size_t)MB * ND;   // Y
    unsigned short* o_h_bt = ub + uoff; uoff += (size_t)MB * ND;
    unsigned short* Yw_bb  = ub + uoff; uoff += (size_t)MB * ND;
    unsigned short* OHWh_bt= ub + uoff; uoff += (size_t)MB * ND;
    unsigned short* OHGI_bt= ub + uoff; uoff += (size_t)MB * G3;
    unsigned short* h16a   = ub + uoff; uoff += (size_t)B_SZ * ND;
    unsigned short* h16b   = ub + uoff; uoff += (size_t)B_SZ * ND;
    unsigned short* pWih_b = ub + uoff; uoff += (size_t)G3 * 320;
    unsigned short* hWih_b = ub + uoff; uoff += (size_t)G3 * 320;
    unsigned short* pWhh_b = ub + uoff; uoff += (size_t)G3 * ND;
    unsigned short* hWhh_b = ub + uoff; uoff += (size_t)G3 * ND;
    unsigned short* mWihR  = ub + uoff; uoff += (size_t)G3 * ND;
    unsigned short* WyT_b  = ub + uoff; uoff += (size_t)ND * ND;
    unsigned short* WhT_b  = ub + uoff; uoff += (size_t)ND * ND;
    unsigned short* Ws_p   = ub + uoff; uoff += 64L * 512 * 8;
    unsigned short* Wg_p   = ub + uoff; uoff += 6L * 64 * 512 * 8;
    off += (uoff + 1) / 2;
    if (ws_size < off * sizeof(float)) return;

    auto cblk = [](long n) { return (int)((n + 255) / 256); };

    // ---- prep ----
    prep_idx<<<cblk(MB), 256, 0, stream>>>(prem, hyp, idx_p, idx_h);
    conv_w <<<cblk((long)G3 * 320), 256, 0, stream>>>(p_Wih, pWih_b, G3, EMBD, 320, EMBD, 0);
    conv_w <<<cblk((long)G3 * 320), 256, 0, stream>>>(h_Wih, hWih_b, G3, EMBD, 320, EMBD, 0);
    conv_w <<<cblk((long)G3 * ND), 256, 0, stream>>>(p_Whh, pWhh_b, G3, ND, ND, ND, 0);
    conv_w <<<cblk((long)G3 * ND), 256, 0, stream>>>(h_Whh, hWhh_b, G3, ND, ND, ND, 0);
    conv_w <<<cblk((long)G3 * ND), 256, 0, stream>>>(m_Wih, mWihR, G3, ND, ND, 2 * ND, ND);
    conv_wT<<<cblk((long)ND * ND), 256, 0, stream>>>(W_y, WyT_b, ND, ND, ND, ND);
    conv_wT<<<cblk((long)ND * ND), 256, 0, stream>>>(W_h, WhT_b, ND, ND, ND, ND);
    pack_ws<<<cblk(64L * 512 * 8), 256, 0, stream>>>(W_r, Ws_p);
    pack_wg<<<cblk(6L * 64 * 512 * 8), 256, 0, stream>>>(m_Wih, m_Whh, Wg_p);
    zero_kernel<<<cblk(B_SZ * ND), 256, 0, stream>>>(h32, B_SZ * ND);
    zero_kernel<<<cblk(B_SZ * ND / 2), 256, 0, stream>>>((float*)h16a, B_SZ * ND / 2);
    zero_kernel<<<cblk(NFLAGS), 256, 0, stream>>>((float*)flags, NFLAGS);

    // ---- premise ----
    {
        dim3 g(G3 / 64, MB / 64);
        mfma_gemm<float, false><<<g, 256, 0, stream>>>(E, idx_p, pWih_b, p_bih, GI,
                                                       MB, G3, EMBD, EMBD, 320, G3);
    }
    gru_chain<<<GRU_NB, 256, 0, stream>>>(pWhh_b, GI, p_bhh, prem, h32, h16a, h16b,
                                          o_p_bt, flags, FB_GRUP);

    // ---- hypothesis ----
    {
        dim3 g(G3 / 64, MB / 64);
        mfma_gemm<float, false><<<g, 256, 0, stream>>>(E, idx_h, hWih_b, h_bih, GI,
                                                       MB, G3, EMBD, EMBD, 320, G3);
    }
    gru_chain<<<GRU_NB, 256, 0, stream>>>(hWhh_b, GI, h_bhh, hyp, h32, h16a, h16b,
                                          o_h_bt, flags, FB_GRUH);

    // ---- attention precompute (all [b][t]-row layouts) ----
    {
        dim3 g(ND / 64, MB / 64);
        mfma_gemm<unsigned short, true><<<g, 256, 0, stream>>>(o_p_bt, nullptr, WyT_b, nullptr,
                                                               Yw_bb, MB, ND, ND, ND, ND, ND);
        mfma_gemm<unsigned short, true><<<g, 256, 0, stream>>>(o_h_bt, nullptr, WhT_b, nullptr,
                                                               OHWh_bt, MB, ND, ND, ND, ND, ND);
        dim3 g2(G3 / 64, MB / 64);
        mfma_gemm<unsigned short, true><<<g2, 256, 0, stream>>>(o_h_bt, nullptr, mWihR, m_bih,
                                                                OHGI_bt, MB, G3, ND, ND, ND, G3);
    }

    // ---- match: sync-free, one block per batch element ----
    match_pb<<<B_SZ, 512, 0, stream>>>(Ws_p, Wg_p, OHWh_bt, OHGI_bt, m_bhh, W_alpha,
                                       Yw_bb, o_p_bt, prem, hyp, r32);

    final_logits<<<B_SZ, 64, 0, stream>>>(r32, out_W, out_b, out);
}